// Round 4
// baseline (2582.126 us; speedup 1.0000x reference)
//
#include <hip/hip_runtime.h>

// ---------------------------------------------------------------------------
// AlignableCaslAgent forward: conv towers (video/audio) -> LN -> attention
// gating -> masked LSTM cell.  Inputs f32 (flag-verified), OUTPUTS f32.
// Round 3: write d_out as f32 (rounds 2/3 wrote bf16 -> harness read f32,
// giving the deterministic 1.31 error).  Compute pipeline unchanged.
// ---------------------------------------------------------------------------

typedef unsigned short u16;
typedef unsigned int u32;

__device__ __forceinline__ float b2f(u16 u) {
    union { u32 i; float f; } v; v.i = ((u32)u) << 16; return v.f;
}
__device__ __forceinline__ u16 f2b(float f) {
    union { float f; u32 i; } v; v.f = f;
    u32 r = v.i + 0x7fffu + ((v.i >> 16) & 1u);   // round-nearest-even
    return (u16)(r >> 16);
}
// Load element i of a buffer whose dtype is decided at runtime.
__device__ __forceinline__ float ldin(const void* p, long i, bool f32) {
    return f32 ? ((const float*)p)[i] : b2f(((const u16*)p)[i]);
}
__device__ __forceinline__ bool getflag(const int* f) {
    return f != nullptr && *f != 0;
}

// ---------------------------------------------------------------------------
// Dtype sniff: bf16-decode the first 16K u16 words of x.  Exponent field
// >= 0x90 (|v| >= 2^17) cannot occur in this problem's data as bf16 but
// occurs ~44%/word in f32 mantissa halves.  flag=1 -> buffers hold f32.
// ---------------------------------------------------------------------------
__global__ __launch_bounds__(256) void sniff(const u16* __restrict__ x, int* flag)
{
    __shared__ int s;
    if (threadIdx.x == 0) s = 0;
    __syncthreads();
    int hit = 0;
    for (int i = threadIdx.x; i < 16384; i += 256) {
        int e = (x[i] >> 7) & 0xFF;
        if (e >= 0x90) hit = 1;
    }
    if (hit) atomicOr(&s, 1);
    __syncthreads();
    if (threadIdx.x == 0) *flag = s;
}

// ---------------------------------------------------------------------------
// Direct conv + ReLU.  Input batch index = b0 + blockIdx.x (stride sb,
// element offset in_off); output is chunk-local [blockIdx.x][oc][oy*ox] bf16.
// Weights OIHW staged transposed (k-major, oc contiguous) as f32 in LDS so
// weight reads are wave-uniform float4 broadcasts.
// ---------------------------------------------------------------------------
template<int IC, int IH, int IW, int OC, int KH, int KW, int S, int OH, int OW, int ICCH>
__global__ __launch_bounds__(256) void conv_relu(
    const void* __restrict__ in_all, long sb, long in_off, int b0, const int* inflag,
    const void* __restrict__ W, const void* __restrict__ bias, const int* wflag,
    u16* __restrict__ out_all)
{
    constexpr int OP   = OH * OW;
    constexpr int NP   = (OP + 63) / 64;        // pixels per lane
    constexpr int OCG  = OC / 4;                // oc per thread-group
    constexpr int ROWS = ICCH * KH * KW;        // k rows per weight chunk
    constexpr int CH   = IC / ICCH;

    __shared__ u16 ins[IC * IH * IW];
    __shared__ __attribute__((aligned(16))) float wT[ROWS * OC];

    const int b = blockIdx.x;
    const int tid = threadIdx.x;
    const bool inf32 = getflag(inflag);
    const bool wf32  = getflag(wflag);

    const long ibase = (long)(b0 + b) * sb + in_off;
    for (int i = tid; i < IC * IH * IW; i += 256)
        ins[i] = inf32 ? f2b(((const float*)in_all)[ibase + i])
                       : ((const u16*)in_all)[ibase + i];

    const int oc0 = (tid >> 6) * OCG;
    const int ps  = tid & 63;

    float acc[NP][OCG];
    int   pbase[NP];
    bool  pval[NP];
#pragma unroll
    for (int np = 0; np < NP; ++np) {
        int p = ps + 64 * np;
        pval[np] = (p < OP);
        int pp = pval[np] ? p : 0;
        int oy = pp / OW, ox = pp % OW;
        pbase[np] = oy * S * IW + ox * S;
#pragma unroll
        for (int j = 0; j < OCG; ++j) acc[np][j] = ldin(bias, oc0 + j, wf32);
    }

    for (int ch = 0; ch < CH; ++ch) {
        __syncthreads();
        for (int i = tid; i < ROWS * OC; i += 256) {
            int k  = i / OC, oc = i % OC;
            int icl = k / (KH * KW), r = k % (KH * KW);
            wT[i] = ldin(W, ((long)oc * IC + ch * ICCH + icl) * (KH * KW) + r, wf32);
        }
        __syncthreads();

        const int icbase = ch * ICCH * IH * IW;
        int wrow = 0;
        for (int icl = 0; icl < ICCH; ++icl) {
            for (int ky = 0; ky < KH; ++ky) {
                const int rbase = icbase + icl * IH * IW + ky * IW;
#pragma unroll
                for (int kx = 0; kx < KW; ++kx, ++wrow) {
                    const float4* wr = (const float4*)&wT[wrow * OC + oc0];
                    float4 w4[OCG / 4];
#pragma unroll
                    for (int q = 0; q < OCG / 4; ++q) w4[q] = wr[q];
#pragma unroll
                    for (int np = 0; np < NP; ++np) {
                        float xv = b2f(ins[pbase[np] + rbase + kx]);
#pragma unroll
                        for (int q = 0; q < OCG / 4; ++q) {
                            acc[np][q * 4 + 0] += xv * w4[q].x;
                            acc[np][q * 4 + 1] += xv * w4[q].y;
                            acc[np][q * 4 + 2] += xv * w4[q].z;
                            acc[np][q * 4 + 3] += xv * w4[q].w;
                        }
                    }
                }
            }
        }
    }

    const long ob = (long)b * (OC * OP);
#pragma unroll
    for (int np = 0; np < NP; ++np) if (pval[np]) {
        int p = ps + 64 * np;
#pragma unroll
        for (int j = 0; j < OCG; ++j)
            out_all[ob + (long)(oc0 + j) * OP + p] = f2b(fmaxf(acc[np][j], 0.f));
    }
}

// ---------------------------------------------------------------------------
// Tiled GEMM: C[M][N] (f32) = A[M][K] * B[N][K]^T, dtype-flagged operands.
// 64x64 tile, BK=32, 256 threads, 4x4 microtile per thread.  M,N mult of 64.
// ---------------------------------------------------------------------------
__global__ __launch_bounds__(256) void gemm_btk(
    const void* __restrict__ A, const int* aflag,
    const void* __restrict__ Bm, const int* bflag,
    float* __restrict__ C, int M, int N, int K)
{
    __shared__ __attribute__((aligned(16))) float As[32 * 68];
    __shared__ __attribute__((aligned(16))) float Bs[32 * 68];

    const int tid = threadIdx.x;
    const int m0 = blockIdx.y * 64, n0 = blockIdx.x * 64;
    const int tm0 = (tid >> 4) * 4, tn0 = (tid & 15) * 4;
    const bool af32 = getflag(aflag);
    const bool bf32 = getflag(bflag);

    float acc[4][4];
#pragma unroll
    for (int i = 0; i < 4; ++i)
#pragma unroll
        for (int j = 0; j < 4; ++j) acc[i][j] = 0.f;

    for (int k0 = 0; k0 < K; k0 += 32) {
        __syncthreads();
        for (int idx = tid; idx < 2048; idx += 256) {
            int r = idx >> 5, kk = idx & 31;
            As[kk * 68 + r] = ldin(A, (long)(m0 + r) * K + k0 + kk, af32);
            Bs[kk * 68 + r] = ldin(Bm, (long)(n0 + r) * K + k0 + kk, bf32);
        }
        __syncthreads();
#pragma unroll
        for (int kk = 0; kk < 32; ++kk) {
            float4 a = *(const float4*)&As[kk * 68 + tm0];
            float4 b = *(const float4*)&Bs[kk * 68 + tn0];
            acc[0][0] += a.x * b.x; acc[0][1] += a.x * b.y; acc[0][2] += a.x * b.z; acc[0][3] += a.x * b.w;
            acc[1][0] += a.y * b.x; acc[1][1] += a.y * b.y; acc[1][2] += a.y * b.z; acc[1][3] += a.y * b.w;
            acc[2][0] += a.z * b.x; acc[2][1] += a.z * b.y; acc[2][2] += a.z * b.z; acc[2][3] += a.z * b.w;
            acc[3][0] += a.w * b.x; acc[3][1] += a.w * b.y; acc[3][2] += a.w * b.z; acc[3][3] += a.w * b.w;
        }
    }

#pragma unroll
    for (int i = 0; i < 4; ++i)
#pragma unroll
        for (int j = 0; j < 4; ++j)
            C[(long)(m0 + tm0 + i) * N + n0 + tn0 + j] = acc[i][j];
}

// ---------------------------------------------------------------------------
// bias + ReLU + LayerNorm over 512 features, per row.  Writes f32 to the
// d_out slot (pre-shifted to the chunk's first row).
// ---------------------------------------------------------------------------
__global__ __launch_bounds__(256) void ln_relu(
    const float* __restrict__ y,
    const void* __restrict__ bias, const void* __restrict__ g,
    const void* __restrict__ be, const int* flag,
    float* __restrict__ outv)
{
    __shared__ float red[256];
    __shared__ float mean_s, inv_s;

    const int b = blockIdx.x, tid = threadIdx.x;
    const bool f32 = getflag(flag);
    const float* yr = y + (long)b * 512;

    float v0 = fmaxf(yr[tid]       + ldin(bias, tid,       f32), 0.f);
    float v1 = fmaxf(yr[tid + 256] + ldin(bias, tid + 256, f32), 0.f);

    red[tid] = v0 + v1;
    __syncthreads();
    for (int s = 128; s > 0; s >>= 1) { if (tid < s) red[tid] += red[tid + s]; __syncthreads(); }
    if (tid == 0) mean_s = red[0] * (1.f / 512.f);
    __syncthreads();
    float mean = mean_s;
    float d0 = v0 - mean, d1 = v1 - mean;
    red[tid] = d0 * d0 + d1 * d1;
    __syncthreads();
    for (int s = 128; s > 0; s >>= 1) { if (tid < s) red[tid] += red[tid + s]; __syncthreads(); }
    if (tid == 0) inv_s = rsqrtf(red[0] * (1.f / 512.f) + 1e-5f);
    __syncthreads();
    float inv = inv_s;

    outv[(long)b * 512 + tid]       = d0 * inv * ldin(g, tid,       f32) + ldin(be, tid,       f32);
    outv[(long)b * 512 + tid + 256] = d1 * inv * ldin(g, tid + 256, f32) + ldin(be, tid + 256, f32);
}

// ---------------------------------------------------------------------------
// Attention gating -> Acat row = [fused (512) | (1-done)*h0 (128)] bf16.
// vf/af are read back from d_out as f32.  Attention uses UNMASKED h0.
// ---------------------------------------------------------------------------
__global__ __launch_bounds__(256) void attn_fuse(
    const float* __restrict__ vff, const float* __restrict__ aff,
    const void* __restrict__ h0, const void* __restrict__ done,
    const void* __restrict__ avW, const void* __restrict__ avb,
    const void* __restrict__ aaW, const void* __restrict__ aab,
    const void* __restrict__ asW, const void* __restrict__ asb,
    const void* __restrict__ attW, const void* __restrict__ attb,
    const int* flag, u16* __restrict__ Acat)
{
    __shared__ float vs[512], afs[512], hs[128], act[32], wsm[2];
    const int b = blockIdx.x, tid = threadIdx.x;
    const bool f32 = getflag(flag);

    for (int i = tid; i < 512; i += 256) {
        vs[i]  = vff[(long)b * 512 + i];
        afs[i] = aff[(long)b * 512 + i];
    }
    if (tid < 128) hs[tid] = ldin(h0, b * 128 + tid, f32);
    __syncthreads();

    if (tid < 32) {
        float a = ldin(avb, tid, f32) + ldin(aab, tid, f32) + ldin(asb, tid, f32);
        for (int k = 0; k < 512; ++k)
            a += vs[k] * ldin(avW, tid * 512 + k, f32) + afs[k] * ldin(aaW, tid * 512 + k, f32);
        for (int k = 0; k < 128; ++k)
            a += hs[k] * ldin(asW, tid * 128 + k, f32);
        act[tid] = tanhf(a);
    }
    __syncthreads();
    if (tid == 0) {
        float l0 = ldin(attb, 0, f32), l1 = ldin(attb, 1, f32);
        for (int j = 0; j < 32; ++j) {
            l0 += act[j] * ldin(attW, j, f32);
            l1 += act[j] * ldin(attW, 32 + j, f32);
        }
        float mx = fmaxf(l0, l1);
        float e0 = expf(l0 - mx), e1 = expf(l1 - mx);
        float s = e0 + e1;
        wsm[0] = e0 / s; wsm[1] = e1 / s;
    }
    __syncthreads();
    const float w0 = wsm[0], w1 = wsm[1];
    const float m = 1.f - ldin(done, b, f32);
    for (int i = tid; i < 512; i += 256)
        Acat[(long)b * 640 + i] = f2b(w0 * vs[i] + w1 * afs[i]);
    if (tid < 128)
        Acat[(long)b * 640 + 512 + tid] = f2b(m * hs[tid]);
}

// ---------------------------------------------------------------------------
// Pack Bcat[n][640] = [Wih[n][512] | Whh[n][128]] as bf16.
// ---------------------------------------------------------------------------
__global__ __launch_bounds__(256) void pack_bcat(
    const void* __restrict__ Wih, const void* __restrict__ Whh,
    const int* flag, u16* __restrict__ Bcat)
{
    int idx = blockIdx.x * 256 + threadIdx.x;
    if (idx >= 512 * 640) return;
    const bool f32 = getflag(flag);
    int n = idx / 640, k = idx % 640;
    Bcat[idx] = f2b((k < 512) ? ldin(Wih, n * 512 + k, f32)
                              : ldin(Whh, n * 128 + (k - 512), f32));
}

// ---------------------------------------------------------------------------
// LSTM pointwise epilogue (gate order i,f,g,o).  Writes f32 h_new, c_new.
// ---------------------------------------------------------------------------
__global__ __launch_bounds__(128) void lstm_fin(
    const float* __restrict__ gates,
    const void* __restrict__ bih, const void* __restrict__ bhh,
    const void* __restrict__ c0, const void* __restrict__ done,
    const int* flag, float* __restrict__ out)
{
    const int b = blockIdx.x, j = threadIdx.x;
    const bool f32 = getflag(flag);
    const float* G = gates + (long)b * 512;
    float gi = G[j]       + ldin(bih, j,       f32) + ldin(bhh, j,       f32);
    float gf = G[128 + j] + ldin(bih, 128 + j, f32) + ldin(bhh, 128 + j, f32);
    float gg = G[256 + j] + ldin(bih, 256 + j, f32) + ldin(bhh, 256 + j, f32);
    float go = G[384 + j] + ldin(bih, 384 + j, f32) + ldin(bhh, 384 + j, f32);
    float m  = 1.f - ldin(done, b, f32);
    float c  = m * ldin(c0, b * 128 + j, f32);
    float si = 1.f / (1.f + expf(-gi));
    float sf = 1.f / (1.f + expf(-gf));
    float so = 1.f / (1.f + expf(-go));
    float cn = sf * c + si * tanhf(gg);
    float hn = so * tanhf(cn);
    out[b * 128 + j]          = hn;
    out[131072 + b * 128 + j] = cn;
}

// ---------------------------------------------------------------------------
extern "C" void kernel_launch(void* const* d_in, const int* in_sizes, int n_in,
                              void* d_out, int out_size, void* d_ws, size_t ws_size,
                              hipStream_t stream)
{
    (void)in_sizes; (void)n_in; (void)out_size;

    const void* x     = d_in[0];
    const void* done  = d_in[1];
    const void* h0    = d_in[2];
    const void* c0in  = d_in[3];
    const void* vW1   = d_in[4];
    const void* vb1   = d_in[5];
    const void* vW2   = d_in[6];
    const void* vb2   = d_in[7];
    const void* vW3   = d_in[8];
    const void* vb3   = d_in[9];
    const void* vWl   = d_in[10];
    const void* vbl   = d_in[11];
    const void* aW1   = d_in[12];
    const void* ab1   = d_in[13];
    const void* aW2   = d_in[14];
    const void* ab2   = d_in[15];
    const void* aW3   = d_in[16];
    const void* ab3   = d_in[17];
    const void* aWl   = d_in[18];
    const void* abl   = d_in[19];
    const void* vln_g = d_in[20];
    const void* vln_b = d_in[21];
    const void* aln_g = d_in[22];
    const void* aln_b = d_in[23];
    const void* att_vW = d_in[24];
    const void* att_vb = d_in[25];
    const void* att_aW = d_in[26];
    const void* att_ab = d_in[27];
    const void* att_sW = d_in[28];
    const void* att_sb = d_in[29];
    const void* attW  = d_in[30];
    const void* attb  = d_in[31];
    const void* Wih   = d_in[32];
    const void* Whh   = d_in[33];
    const void* bih   = d_in[34];
    const void* bhh   = d_in[35];

    float* out = (float*)d_out;
    float* vf_out = out + 262144;   // vf slot [1024][512] f32
    float* af_out = out + 786432;   // af slot

    // ---- adaptive batch-chunk size so the carve fits ws_size ----
    const size_t PERBATCH = 12800ul * 2 + 5184ul * 2 + 3136ul * 2 + 512ul * 4; // 44288 B
    const size_t PERSIST  = 16 + 1024ul * 512 * 4          // gates f32
                          + 1024ul * 640 * 2               // Acat bf16
                          + 512ul * 640 * 2;               // Bcat bf16
    int NB = 64;
    const int cands[4] = {1024, 512, 256, 128};
    for (int i = 0; i < 4; ++i) {
        if (PERSIST + (size_t)cands[i] * PERBATCH <= ws_size) { NB = cands[i]; break; }
    }
    const int NC = 1024 / NB;

    // ---- workspace carve ----
    char* p = (char*)d_ws;
    int*   flag  = (int*)p;              p += 16;
    float* gates = (float*)p;            p += 1024ul * 512 * 4;
    float* ych   = (float*)p;            p += (size_t)NB * 512 * 4;
    u16*   Acat  = (u16*)p;              p += 1024ul * 640 * 2;
    u16*   Bcat  = (u16*)p;              p += 512ul * 640 * 2;
    u16*   c1    = (u16*)p;              p += (size_t)NB * 12800 * 2;
    u16*   c2    = (u16*)p;              p += (size_t)NB * 5184 * 2;
    u16*   c3    = (u16*)p;

    hipLaunchKernelGGL(sniff, dim3(1), dim3(256), 0, stream, (const u16*)x, flag);
    hipLaunchKernelGGL(pack_bcat, dim3(1280), dim3(256), 0, stream, Wih, Whh, flag, Bcat);

    for (int t = 0; t < 2; ++t) {
        const void* W1 = t ? aW1 : vW1;  const void* b1 = t ? ab1 : vb1;
        const void* W2 = t ? aW2 : vW2;  const void* b2 = t ? ab2 : vb2;
        const void* W3 = t ? aW3 : vW3;  const void* b3 = t ? ab3 : vb3;
        const void* Wl = t ? aWl : vWl;  const void* bl = t ? abl : vbl;
        const void* lg = t ? aln_g : vln_g;
        const void* lb = t ? aln_b : vln_b;
        float* fout = t ? af_out : vf_out;

        for (int cch = 0; cch < NC; ++cch) {
            const int b0 = cch * NB;

            hipLaunchKernelGGL((conv_relu<1, 84, 84, 32, 8, 8, 4, 20, 20, 1>),
                dim3(NB), dim3(256), 0, stream,
                x, (long)(2 * 7056), (long)(t * 7056), b0, flag, W1, b1, flag, c1);

            hipLaunchKernelGGL((conv_relu<32, 20, 20, 64, 4, 4, 2, 9, 9, 8>),
                dim3(NB), dim3(256), 0, stream,
                c1, (long)12800, 0l, 0, nullptr, W2, b2, flag, c2);

            hipLaunchKernelGGL((conv_relu<64, 9, 9, 64, 3, 3, 1, 7, 7, 16>),
                dim3(NB), dim3(256), 0, stream,
                c2, (long)5184, 0l, 0, nullptr, W3, b3, flag, c3);

            hipLaunchKernelGGL(gemm_btk, dim3(8, NB / 64), dim3(256), 0, stream,
                c3, nullptr, Wl, flag, ych, NB, 512, 3136);

            hipLaunchKernelGGL(ln_relu, dim3(NB), dim3(256), 0, stream,
                ych, bl, lg, lb, flag, fout + (long)b0 * 512);
        }
    }

    // attention gating -> Acat = [fused | masked h]
    hipLaunchKernelGGL(attn_fuse, dim3(1024), dim3(256), 0, stream,
        vf_out, af_out, h0, done,
        att_vW, att_vb, att_aW, att_ab, att_sW, att_sb, attW, attb, flag, Acat);

    // gates = Acat @ Bcat^T   (M=1024, N=512, K=640)
    hipLaunchKernelGGL(gemm_btk, dim3(8, 16), dim3(256), 0, stream,
        Acat, nullptr, Bcat, nullptr, gates, 1024, 512, 640);

    hipLaunchKernelGGL(lstm_fin, dim3(1024), dim3(128), 0, stream,
        gates, bih, bhh, c0in, done, flag, out);
}

// Round 5
// 1540.850 us; speedup vs baseline: 1.6758x; 1.6758x over previous
//
#include <hip/hip_runtime.h>

// ---------------------------------------------------------------------------
// AlignableCaslAgent forward: conv towers (video/audio) -> LN -> attention
// gating -> masked LSTM cell.  Inputs f32 (flag-verified), outputs f32.
// Round 4: MFMA GEMM (128x128 tile, 16x16x32 bf16) replaces scalar gemm_btk;
// parallelized attention kernel.  Convs still scalar (next target).
// ---------------------------------------------------------------------------

typedef unsigned short u16;
typedef unsigned int u32;
typedef __attribute__((ext_vector_type(8))) short bf16x8;
typedef __attribute__((ext_vector_type(4))) float f32x4;

__device__ __forceinline__ float b2f(u16 u) {
    union { u32 i; float f; } v; v.i = ((u32)u) << 16; return v.f;
}
__device__ __forceinline__ u16 f2b(float f) {
    union { float f; u32 i; } v; v.f = f;
    u32 r = v.i + 0x7fffu + ((v.i >> 16) & 1u);   // round-nearest-even
    return (u16)(r >> 16);
}
__device__ __forceinline__ float ldin(const void* p, long i, bool f32) {
    return f32 ? ((const float*)p)[i] : b2f(((const u16*)p)[i]);
}
__device__ __forceinline__ bool getflag(const int* f) {
    return f != nullptr && *f != 0;
}

// ---------------------------------------------------------------------------
// Dtype sniff (kept for robustness; verified f32 on this harness).
// ---------------------------------------------------------------------------
__global__ __launch_bounds__(256) void sniff(const u16* __restrict__ x, int* flag)
{
    __shared__ int s;
    if (threadIdx.x == 0) s = 0;
    __syncthreads();
    int hit = 0;
    for (int i = threadIdx.x; i < 16384; i += 256) {
        int e = (x[i] >> 7) & 0xFF;
        if (e >= 0x90) hit = 1;
    }
    if (hit) atomicOr(&s, 1);
    __syncthreads();
    if (threadIdx.x == 0) *flag = s;
}

// ---------------------------------------------------------------------------
// Direct conv + ReLU (unchanged from round 3).
// ---------------------------------------------------------------------------
template<int IC, int IH, int IW, int OC, int KH, int KW, int S, int OH, int OW, int ICCH>
__global__ __launch_bounds__(256) void conv_relu(
    const void* __restrict__ in_all, long sb, long in_off, int b0, const int* inflag,
    const void* __restrict__ W, const void* __restrict__ bias, const int* wflag,
    u16* __restrict__ out_all)
{
    constexpr int OP   = OH * OW;
    constexpr int NP   = (OP + 63) / 64;
    constexpr int OCG  = OC / 4;
    constexpr int ROWS = ICCH * KH * KW;
    constexpr int CH   = IC / ICCH;

    __shared__ u16 ins[IC * IH * IW];
    __shared__ __attribute__((aligned(16))) float wT[ROWS * OC];

    const int b = blockIdx.x;
    const int tid = threadIdx.x;
    const bool inf32 = getflag(inflag);
    const bool wf32  = getflag(wflag);

    const long ibase = (long)(b0 + b) * sb + in_off;
    for (int i = tid; i < IC * IH * IW; i += 256)
        ins[i] = inf32 ? f2b(((const float*)in_all)[ibase + i])
                       : ((const u16*)in_all)[ibase + i];

    const int oc0 = (tid >> 6) * OCG;
    const int ps  = tid & 63;

    float acc[NP][OCG];
    int   pbase[NP];
    bool  pval[NP];
#pragma unroll
    for (int np = 0; np < NP; ++np) {
        int p = ps + 64 * np;
        pval[np] = (p < OP);
        int pp = pval[np] ? p : 0;
        int oy = pp / OW, ox = pp % OW;
        pbase[np] = oy * S * IW + ox * S;
#pragma unroll
        for (int j = 0; j < OCG; ++j) acc[np][j] = ldin(bias, oc0 + j, wf32);
    }

    for (int ch = 0; ch < CH; ++ch) {
        __syncthreads();
        for (int i = tid; i < ROWS * OC; i += 256) {
            int k  = i / OC, oc = i % OC;
            int icl = k / (KH * KW), r = k % (KH * KW);
            wT[i] = ldin(W, ((long)oc * IC + ch * ICCH + icl) * (KH * KW) + r, wf32);
        }
        __syncthreads();

        const int icbase = ch * ICCH * IH * IW;
        int wrow = 0;
        for (int icl = 0; icl < ICCH; ++icl) {
            for (int ky = 0; ky < KH; ++ky) {
                const int rbase = icbase + icl * IH * IW + ky * IW;
#pragma unroll
                for (int kx = 0; kx < KW; ++kx, ++wrow) {
                    const float4* wr = (const float4*)&wT[wrow * OC + oc0];
                    float4 w4[OCG / 4];
#pragma unroll
                    for (int q = 0; q < OCG / 4; ++q) w4[q] = wr[q];
#pragma unroll
                    for (int np = 0; np < NP; ++np) {
                        float xv = b2f(ins[pbase[np] + rbase + kx]);
#pragma unroll
                        for (int q = 0; q < OCG / 4; ++q) {
                            acc[np][q * 4 + 0] += xv * w4[q].x;
                            acc[np][q * 4 + 1] += xv * w4[q].y;
                            acc[np][q * 4 + 2] += xv * w4[q].z;
                            acc[np][q * 4 + 3] += xv * w4[q].w;
                        }
                    }
                }
            }
        }
    }

    const long ob = (long)b * (OC * OP);
#pragma unroll
    for (int np = 0; np < NP; ++np) if (pval[np]) {
        int p = ps + 64 * np;
#pragma unroll
        for (int j = 0; j < OCG; ++j)
            out_all[ob + (long)(oc0 + j) * OP + p] = f2b(fmaxf(acc[np][j], 0.f));
    }
}

// ---------------------------------------------------------------------------
// MFMA GEMM: C[M][N] f32 = A[M][K] bf16 * (B[N][K])^T bf16.
// 128x128 tile, BK=32, 256 threads = 4 waves in 2x2 of 64x64 quadrants,
// each wave 4x4 grid of 16x16x32 bf16 MFMAs.  K % 32 == 0, N % 128 == 0,
// M arbitrary (row clamp on load, mask on store).
// LDS rows padded to 40 elems (80 B) -> 2-way bank aliasing (free).
// ---------------------------------------------------------------------------
#define LDSP 40
__global__ __launch_bounds__(256) void gemm_mfma(
    const u16* __restrict__ A, const u16* __restrict__ B,
    float* __restrict__ C, int M, int N, int K)
{
    __shared__ __attribute__((aligned(16))) u16 As[128 * LDSP];
    __shared__ __attribute__((aligned(16))) u16 Bs[128 * LDSP];

    const int tid  = threadIdx.x;
    const int wave = tid >> 6, lane = tid & 63;
    const int quad = lane >> 4, l16 = lane & 15;
    const int m0 = blockIdx.y * 128, n0 = blockIdx.x * 128;
    const int wm = (wave >> 1) * 64, wn = (wave & 1) * 64;

    f32x4 acc[4][4];
#pragma unroll
    for (int mi = 0; mi < 4; ++mi)
#pragma unroll
        for (int ni = 0; ni < 4; ++ni) {
            acc[mi][ni][0] = 0.f; acc[mi][ni][1] = 0.f;
            acc[mi][ni][2] = 0.f; acc[mi][ni][3] = 0.f;
        }

    for (int k0 = 0; k0 < K; k0 += 32) {
        __syncthreads();
#pragma unroll
        for (int pass = 0; pass < 2; ++pass) {
            int idx = tid + pass * 256;          // 0..511
            int r = idx >> 2, seg = idx & 3;     // row 0..127, 16B seg 0..3
            int gr = m0 + r; if (gr > M - 1) gr = M - 1;
            uint4 va = *(const uint4*)(A + (long)gr * K + k0 + seg * 8);
            *(uint4*)(As + r * LDSP + seg * 8) = va;
            uint4 vb = *(const uint4*)(B + (long)(n0 + r) * K + k0 + seg * 8);
            *(uint4*)(Bs + r * LDSP + seg * 8) = vb;
        }
        __syncthreads();

        bf16x8 af[4], bfr[4];
#pragma unroll
        for (int mi = 0; mi < 4; ++mi)
            af[mi] = *(const bf16x8*)(As + (wm + mi * 16 + l16) * LDSP + quad * 8);
#pragma unroll
        for (int ni = 0; ni < 4; ++ni)
            bfr[ni] = *(const bf16x8*)(Bs + (wn + ni * 16 + l16) * LDSP + quad * 8);
#pragma unroll
        for (int mi = 0; mi < 4; ++mi)
#pragma unroll
            for (int ni = 0; ni < 4; ++ni)
                acc[mi][ni] = __builtin_amdgcn_mfma_f32_16x16x32_bf16(
                    af[mi], bfr[ni], acc[mi][ni], 0, 0, 0);
    }

    // C/D layout: col = lane&15, row = quad*4 + reg   [verified m89]
#pragma unroll
    for (int mi = 0; mi < 4; ++mi) {
#pragma unroll
        for (int ni = 0; ni < 4; ++ni) {
            int col = n0 + wn + ni * 16 + l16;
#pragma unroll
            for (int r = 0; r < 4; ++r) {
                int row = m0 + wm + mi * 16 + quad * 4 + r;
                if (row < M) C[(long)row * N + col] = acc[mi][ni][r];
            }
        }
    }
}

// ---------------------------------------------------------------------------
// Pack a f32/bf16-flagged weight matrix [N][K] into bf16.
// ---------------------------------------------------------------------------
__global__ __launch_bounds__(256) void pack_bf16(
    const void* __restrict__ src, const int* flag, u16* __restrict__ dst, long n)
{
    long idx = (long)blockIdx.x * 256 + threadIdx.x;
    if (idx < n) dst[idx] = f2b(ldin(src, idx, getflag(flag)));
}

// ---------------------------------------------------------------------------
// bias + ReLU + LayerNorm over 512 features, per row.  Writes f32 to d_out.
// ---------------------------------------------------------------------------
__global__ __launch_bounds__(256) void ln_relu(
    const float* __restrict__ y,
    const void* __restrict__ bias, const void* __restrict__ g,
    const void* __restrict__ be, const int* flag,
    float* __restrict__ outv)
{
    __shared__ float red[256];
    __shared__ float mean_s, inv_s;

    const int b = blockIdx.x, tid = threadIdx.x;
    const bool f32 = getflag(flag);
    const float* yr = y + (long)b * 512;

    float v0 = fmaxf(yr[tid]       + ldin(bias, tid,       f32), 0.f);
    float v1 = fmaxf(yr[tid + 256] + ldin(bias, tid + 256, f32), 0.f);

    red[tid] = v0 + v1;
    __syncthreads();
    for (int s = 128; s > 0; s >>= 1) { if (tid < s) red[tid] += red[tid + s]; __syncthreads(); }
    if (tid == 0) mean_s = red[0] * (1.f / 512.f);
    __syncthreads();
    float mean = mean_s;
    float d0 = v0 - mean, d1 = v1 - mean;
    red[tid] = d0 * d0 + d1 * d1;
    __syncthreads();
    for (int s = 128; s > 0; s >>= 1) { if (tid < s) red[tid] += red[tid + s]; __syncthreads(); }
    if (tid == 0) inv_s = rsqrtf(red[0] * (1.f / 512.f) + 1e-5f);
    __syncthreads();
    float inv = inv_s;

    outv[(long)b * 512 + tid]       = d0 * inv * ldin(g, tid,       f32) + ldin(be, tid,       f32);
    outv[(long)b * 512 + tid + 256] = d1 * inv * ldin(g, tid + 256, f32) + ldin(be, tid + 256, f32);
}

// ---------------------------------------------------------------------------
// Attention gating -> Acat row = [fused (512) | (1-done)*h0 (128)] bf16.
// 256 threads: 8-way K-split (g = tid>>5) per output unit (j = tid&31),
// LDS reduction.  Attention uses UNMASKED h0.
// ---------------------------------------------------------------------------
__global__ __launch_bounds__(256) void attn_fuse(
    const float* __restrict__ vff, const float* __restrict__ aff,
    const void* __restrict__ h0, const void* __restrict__ done,
    const void* __restrict__ avW, const void* __restrict__ avb,
    const void* __restrict__ aaW, const void* __restrict__ aab,
    const void* __restrict__ asW, const void* __restrict__ asb,
    const void* __restrict__ attW, const void* __restrict__ attb,
    const int* flag, u16* __restrict__ Acat)
{
    __shared__ float vs[512], afs[512], hs[128], part[8][32], act[32], wsm[2];
    const int b = blockIdx.x, tid = threadIdx.x;
    const bool f32 = getflag(flag);

    for (int i = tid; i < 512; i += 256) {
        vs[i]  = vff[(long)b * 512 + i];
        afs[i] = aff[(long)b * 512 + i];
    }
    if (tid < 128) hs[tid] = ldin(h0, b * 128 + tid, f32);
    __syncthreads();

    {
        const int j = tid & 31, g = tid >> 5;
        float a = 0.f;
        for (int k = g * 64; k < g * 64 + 64; ++k)
            a += vs[k] * ldin(avW, j * 512 + k, f32) + afs[k] * ldin(aaW, j * 512 + k, f32);
        for (int k = g * 16; k < g * 16 + 16; ++k)
            a += hs[k] * ldin(asW, j * 128 + k, f32);
        part[g][j] = a;
    }
    __syncthreads();
    if (tid < 32) {
        float a = ldin(avb, tid, f32) + ldin(aab, tid, f32) + ldin(asb, tid, f32);
#pragma unroll
        for (int g2 = 0; g2 < 8; ++g2) a += part[g2][tid];
        act[tid] = tanhf(a);
    }
    __syncthreads();
    if (tid == 0) {
        float l0 = ldin(attb, 0, f32), l1 = ldin(attb, 1, f32);
        for (int j = 0; j < 32; ++j) {
            l0 += act[j] * ldin(attW, j, f32);
            l1 += act[j] * ldin(attW, 32 + j, f32);
        }
        float mx = fmaxf(l0, l1);
        float e0 = expf(l0 - mx), e1 = expf(l1 - mx);
        float s = e0 + e1;
        wsm[0] = e0 / s; wsm[1] = e1 / s;
    }
    __syncthreads();
    const float w0 = wsm[0], w1 = wsm[1];
    const float m = 1.f - ldin(done, b, f32);
    for (int i = tid; i < 512; i += 256)
        Acat[(long)b * 640 + i] = f2b(w0 * vs[i] + w1 * afs[i]);
    if (tid < 128)
        Acat[(long)b * 640 + 512 + tid] = f2b(m * hs[tid]);
}

// ---------------------------------------------------------------------------
// Pack Bcat[n][640] = [Wih[n][512] | Whh[n][128]] as bf16.
// ---------------------------------------------------------------------------
__global__ __launch_bounds__(256) void pack_bcat(
    const void* __restrict__ Wih, const void* __restrict__ Whh,
    const int* flag, u16* __restrict__ Bcat)
{
    int idx = blockIdx.x * 256 + threadIdx.x;
    if (idx >= 512 * 640) return;
    const bool f32 = getflag(flag);
    int n = idx / 640, k = idx % 640;
    Bcat[idx] = f2b((k < 512) ? ldin(Wih, n * 512 + k, f32)
                              : ldin(Whh, n * 128 + (k - 512), f32));
}

// ---------------------------------------------------------------------------
// LSTM pointwise epilogue (gate order i,f,g,o).  Writes f32 h_new, c_new.
// ---------------------------------------------------------------------------
__global__ __launch_bounds__(128) void lstm_fin(
    const float* __restrict__ gates,
    const void* __restrict__ bih, const void* __restrict__ bhh,
    const void* __restrict__ c0, const void* __restrict__ done,
    const int* flag, float* __restrict__ out)
{
    const int b = blockIdx.x, j = threadIdx.x;
    const bool f32 = getflag(flag);
    const float* G = gates + (long)b * 512;
    float gi = G[j]       + ldin(bih, j,       f32) + ldin(bhh, j,       f32);
    float gf = G[128 + j] + ldin(bih, 128 + j, f32) + ldin(bhh, 128 + j, f32);
    float gg = G[256 + j] + ldin(bih, 256 + j, f32) + ldin(bhh, 256 + j, f32);
    float go = G[384 + j] + ldin(bih, 384 + j, f32) + ldin(bhh, 384 + j, f32);
    float m  = 1.f - ldin(done, b, f32);
    float c  = m * ldin(c0, b * 128 + j, f32);
    float si = 1.f / (1.f + expf(-gi));
    float sf = 1.f / (1.f + expf(-gf));
    float so = 1.f / (1.f + expf(-go));
    float cn = sf * c + si * tanhf(gg);
    float hn = so * tanhf(cn);
    out[b * 128 + j]          = hn;
    out[131072 + b * 128 + j] = cn;
}

// ---------------------------------------------------------------------------
extern "C" void kernel_launch(void* const* d_in, const int* in_sizes, int n_in,
                              void* d_out, int out_size, void* d_ws, size_t ws_size,
                              hipStream_t stream)
{
    (void)in_sizes; (void)n_in; (void)out_size;

    const void* x     = d_in[0];
    const void* done  = d_in[1];
    const void* h0    = d_in[2];
    const void* c0in  = d_in[3];
    const void* vW1   = d_in[4];
    const void* vb1   = d_in[5];
    const void* vW2   = d_in[6];
    const void* vb2   = d_in[7];
    const void* vW3   = d_in[8];
    const void* vb3   = d_in[9];
    const void* vWl   = d_in[10];
    const void* vbl   = d_in[11];
    const void* aW1   = d_in[12];
    const void* ab1   = d_in[13];
    const void* aW2   = d_in[14];
    const void* ab2   = d_in[15];
    const void* aW3   = d_in[16];
    const void* ab3   = d_in[17];
    const void* aWl   = d_in[18];
    const void* abl   = d_in[19];
    const void* vln_g = d_in[20];
    const void* vln_b = d_in[21];
    const void* aln_g = d_in[22];
    const void* aln_b = d_in[23];
    const void* att_vW = d_in[24];
    const void* att_vb = d_in[25];
    const void* att_aW = d_in[26];
    const void* att_ab = d_in[27];
    const void* att_sW = d_in[28];
    const void* att_sb = d_in[29];
    const void* attW  = d_in[30];
    const void* attb  = d_in[31];
    const void* Wih   = d_in[32];
    const void* Whh   = d_in[33];
    const void* bih   = d_in[34];
    const void* bhh   = d_in[35];

    float* out = (float*)d_out;
    float* vf_out = out + 262144;   // vf slot [1024][512] f32
    float* af_out = out + 786432;   // af slot

    // ---- adaptive batch-chunk size so the carve fits ws_size ----
    const size_t PERBATCH = 12800ul * 2 + 5184ul * 2 + 3136ul * 2 + 512ul * 4; // 44288 B
    const size_t PERSIST  = 16 + 1024ul * 512 * 4          // gates f32
                          + 1024ul * 640 * 2               // Acat bf16
                          + 512ul * 640 * 2                // Bcat bf16
                          + 2ul * 512 * 3136 * 2;          // Wlb bf16 (both towers)
    int NB = 64;
    const int cands[4] = {1024, 512, 256, 128};
    for (int i = 0; i < 4; ++i) {
        if (PERSIST + (size_t)cands[i] * PERBATCH <= ws_size) { NB = cands[i]; break; }
    }
    const int NC = 1024 / NB;

    // ---- workspace carve ----
    char* p = (char*)d_ws;
    int*   flag  = (int*)p;              p += 16;
    float* gates = (float*)p;            p += 1024ul * 512 * 4;
    float* ych   = (float*)p;            p += (size_t)NB * 512 * 4;
    u16*   Acat  = (u16*)p;              p += 1024ul * 640 * 2;
    u16*   Bcat  = (u16*)p;              p += 512ul * 640 * 2;
    u16*   Wlb   = (u16*)p;              p += 2ul * 512 * 3136 * 2;
    u16*   c1    = (u16*)p;              p += (size_t)NB * 12800 * 2;
    u16*   c2    = (u16*)p;              p += (size_t)NB * 5184 * 2;
    u16*   c3    = (u16*)p;

    hipLaunchKernelGGL(sniff, dim3(1), dim3(256), 0, stream, (const u16*)x, flag);
    hipLaunchKernelGGL(pack_bcat, dim3(1280), dim3(256), 0, stream, Wih, Whh, flag, Bcat);
    // pack linear weights to bf16: Wlb[0] = vWl, Wlb[1] = aWl
    hipLaunchKernelGGL(pack_bf16, dim3((512ul * 3136 + 255) / 256), dim3(256), 0, stream,
        vWl, flag, Wlb, 512l * 3136);
    hipLaunchKernelGGL(pack_bf16, dim3((512ul * 3136 + 255) / 256), dim3(256), 0, stream,
        aWl, flag, Wlb + 512ul * 3136, 512l * 3136);

    for (int t = 0; t < 2; ++t) {
        const void* W1 = t ? aW1 : vW1;  const void* b1 = t ? ab1 : vb1;
        const void* W2 = t ? aW2 : vW2;  const void* b2 = t ? ab2 : vb2;
        const void* W3 = t ? aW3 : vW3;  const void* b3 = t ? ab3 : vb3;
        const void* bl = t ? abl : vbl;
        const void* lg = t ? aln_g : vln_g;
        const void* lb = t ? aln_b : vln_b;
        float* fout = t ? af_out : vf_out;

        for (int cch = 0; cch < NC; ++cch) {
            const int b0 = cch * NB;

            hipLaunchKernelGGL((conv_relu<1, 84, 84, 32, 8, 8, 4, 20, 20, 1>),
                dim3(NB), dim3(256), 0, stream,
                x, (long)(2 * 7056), (long)(t * 7056), b0, flag, W1, b1, flag, c1);

            hipLaunchKernelGGL((conv_relu<32, 20, 20, 64, 4, 4, 2, 9, 9, 8>),
                dim3(NB), dim3(256), 0, stream,
                c1, (long)12800, 0l, 0, nullptr, W2, b2, flag, c2);

            hipLaunchKernelGGL((conv_relu<64, 9, 9, 64, 3, 3, 1, 7, 7, 16>),
                dim3(NB), dim3(256), 0, stream,
                c2, (long)5184, 0l, 0, nullptr, W3, b3, flag, c3);

            // ych[NB][512] = c3[NB][3136] @ Wlb[t]^T   (MFMA)
            hipLaunchKernelGGL(gemm_mfma, dim3(4, (NB + 127) / 128), dim3(256), 0, stream,
                c3, Wlb + (size_t)t * 512 * 3136, ych, NB, 512, 3136);

            hipLaunchKernelGGL(ln_relu, dim3(NB), dim3(256), 0, stream,
                ych, bl, lg, lb, flag, fout + (long)b0 * 512);
        }
    }

    // attention gating -> Acat = [fused | masked h]
    hipLaunchKernelGGL(attn_fuse, dim3(1024), dim3(256), 0, stream,
        vf_out, af_out, h0, done,
        att_vW, att_vb, att_aW, att_ab, att_sW, att_sb, attW, attb, flag, Acat);

    // gates = Acat @ Bcat^T   (M=1024, N=512, K=640)  (MFMA)
    hipLaunchKernelGGL(gemm_mfma, dim3(4, 8), dim3(256), 0, stream,
        Acat, Bcat, gates, 1024, 512, 640);

    hipLaunchKernelGGL(lstm_fin, dim3(1024), dim3(128), 0, stream,
        gates, bih, bhh, c0in, done, flag, out);
}

// Round 6
// 600.024 us; speedup vs baseline: 4.3034x; 2.5680x over previous
//
#include <hip/hip_runtime.h>

// ---------------------------------------------------------------------------
// AlignableCaslAgent forward.  Inputs f32 (flag-verified), outputs f32.
// Round 5: all convs become implicit-im2col MFMA GEMMs over NHWC
// activations; weights pre-permuted to (oc,ky,kx,ic) k-order; linear weight
// permuted to NHWC-flat; split-K atomic GEMMs fix grid starvation.
// ---------------------------------------------------------------------------

typedef unsigned short u16;
typedef unsigned int u32;
typedef __attribute__((ext_vector_type(8))) short bf16x8;
typedef __attribute__((ext_vector_type(4))) float f32x4;

__device__ __forceinline__ float b2f(u16 u) {
    union { u32 i; float f; } v; v.i = ((u32)u) << 16; return v.f;
}
__device__ __forceinline__ u16 f2b(float f) {
    union { float f; u32 i; } v; v.f = f;
    u32 r = v.i + 0x7fffu + ((v.i >> 16) & 1u);
    return (u16)(r >> 16);
}
__device__ __forceinline__ float ldin(const void* p, long i, bool f32) {
    return f32 ? ((const float*)p)[i] : b2f(((const u16*)p)[i]);
}
__device__ __forceinline__ bool getflag(const int* f) {
    return f != nullptr && *f != 0;
}

// ---------------------------------------------------------------------------
__global__ __launch_bounds__(256) void sniff(const u16* __restrict__ x, int* flag)
{
    __shared__ int s;
    if (threadIdx.x == 0) s = 0;
    __syncthreads();
    int hit = 0;
    for (int i = threadIdx.x; i < 16384; i += 256) {
        int e = (x[i] >> 7) & 0xFF;
        if (e >= 0x90) hit = 1;
    }
    if (hit) atomicOr(&s, 1);
    __syncthreads();
    if (threadIdx.x == 0) *flag = s;
}

__global__ __launch_bounds__(256) void zero_f32(float* __restrict__ p, long n)
{
    long i = (long)blockIdx.x * 256 + threadIdx.x;
    if (i < n) p[i] = 0.f;
}

// ---------------------------------------------------------------------------
// conv1 as implicit-im2col MFMA: x f32 [b][2][84][84] (tower slice), K=64
// (k = ky*8+kx), N=32, S=4, out c1 NHWC bf16 [m][32], m = b*400 + oy*20+ox.
// ---------------------------------------------------------------------------
__global__ __launch_bounds__(256) void conv1_mfma(
    const void* __restrict__ in_all, long in_off, const int* inflag,
    const u16* __restrict__ Wp,          // [32][64] bf16
    const void* __restrict__ bias, const int* bflag,
    u16* __restrict__ outp, int Mtot)
{
    __shared__ __attribute__((aligned(16))) u16 As[128 * 40];

    const int tid = threadIdx.x;
    const int wave = tid >> 6, lane = tid & 63, quad = lane >> 4, l16 = lane & 15;
    const int m0 = blockIdx.x * 128;
    const bool inf32 = getflag(inflag);

    const int r = tid >> 1, h = tid & 1;
    int m = m0 + r; if (m > Mtot - 1) m = Mtot - 1;
    const int b = m / 400, p = m % 400;
    const int oy = p / 20, ox = p % 20;
    const long fbase = in_off + (long)b * 14112 + (long)(oy * 4) * 84 + ox * 4;

    f32x4 acc[2][2];
#pragma unroll
    for (int mi = 0; mi < 2; ++mi)
#pragma unroll
        for (int ni = 0; ni < 2; ++ni)
            acc[mi][ni] = (f32x4){0.f, 0.f, 0.f, 0.f};

#pragma unroll
    for (int ks = 0; ks < 2; ++ks) {
        const int k0 = ks * 32;
        __syncthreads();
        {
            u16 tmp[16];
            const int kbase = k0 + h * 16;        // two ky rows of 8
            if (inf32) {
                const float* F = (const float*)in_all + fbase;
#pragma unroll
                for (int rr = 0; rr < 2; ++rr) {
                    const int ky = (kbase >> 3) + rr;
                    float4 v0 = *(const float4*)(F + ky * 84);
                    float4 v1 = *(const float4*)(F + ky * 84 + 4);
                    tmp[rr * 8 + 0] = f2b(v0.x); tmp[rr * 8 + 1] = f2b(v0.y);
                    tmp[rr * 8 + 2] = f2b(v0.z); tmp[rr * 8 + 3] = f2b(v0.w);
                    tmp[rr * 8 + 4] = f2b(v1.x); tmp[rr * 8 + 5] = f2b(v1.y);
                    tmp[rr * 8 + 6] = f2b(v1.z); tmp[rr * 8 + 7] = f2b(v1.w);
                }
            } else {
                const u16* F = (const u16*)in_all + fbase;
#pragma unroll
                for (int j = 0; j < 16; ++j) {
                    const int k = kbase + j;
                    tmp[j] = F[(k >> 3) * 84 + (k & 7)];
                }
            }
            uint4* dst = (uint4*)(As + r * 40 + h * 16);
            dst[0] = ((const uint4*)tmp)[0];
            dst[1] = ((const uint4*)tmp)[1];
        }
        __syncthreads();

        bf16x8 af[2], bf[2];
#pragma unroll
        for (int mi = 0; mi < 2; ++mi)
            af[mi] = *(const bf16x8*)(As + (wave * 32 + mi * 16 + l16) * 40 + quad * 8);
#pragma unroll
        for (int ni = 0; ni < 2; ++ni)
            bf[ni] = *(const bf16x8*)(Wp + (ni * 16 + l16) * 64 + k0 + quad * 8);
#pragma unroll
        for (int mi = 0; mi < 2; ++mi)
#pragma unroll
            for (int ni = 0; ni < 2; ++ni)
                acc[mi][ni] = __builtin_amdgcn_mfma_f32_16x16x32_bf16(
                    af[mi], bf[ni], acc[mi][ni], 0, 0, 0);
    }

    const bool bf32 = getflag(bflag);
#pragma unroll
    for (int mi = 0; mi < 2; ++mi)
#pragma unroll
        for (int ni = 0; ni < 2; ++ni) {
            const int col = ni * 16 + l16;
            const float bv = ldin(bias, col, bf32);
#pragma unroll
            for (int rr = 0; rr < 4; ++rr) {
                const int row = m0 + wave * 32 + mi * 16 + quad * 4 + rr;
                if (row < Mtot)
                    outp[(long)row * 32 + col] = f2b(fmaxf(acc[mi][ni][rr] + bv, 0.f));
            }
        }
}

// ---------------------------------------------------------------------------
// Generic NHWC bf16 conv as implicit-im2col MFMA.
// in: [b][IH][IW][IC] bf16, Wp: [OC][K] bf16 with k = (ky*KW+kx)*IC + ic.
// out: [m][OC] bf16, m = b*OH*OW + oy*OW + ox.  IC % 32 == 0.
// ---------------------------------------------------------------------------
template<int IC, int IH, int IW, int OC, int KH, int KW, int S, int OH, int OW>
__global__ __launch_bounds__(256) void convN_mfma(
    const u16* __restrict__ in, const u16* __restrict__ Wp,
    const void* __restrict__ bias, const int* bflag,
    u16* __restrict__ outp, int Mtot)
{
    constexpr int OP = OH * OW;
    constexpr int K  = KH * KW * IC;
    constexpr int NF = OC / 16;

    __shared__ __attribute__((aligned(16))) u16 As[128 * 40];

    const int tid = threadIdx.x;
    const int wave = tid >> 6, lane = tid & 63, quad = lane >> 4, l16 = lane & 15;
    const int m0 = blockIdx.x * 128;

    const int r = tid >> 1, h = tid & 1;
    int m = m0 + r; if (m > Mtot - 1) m = Mtot - 1;
    const int b = m / OP, p = m % OP;
    const int oy = p / OW, ox = p % OW;
    const u16* abase = in + (((long)b * IH + oy * S) * IW + ox * S) * IC + h * 16;

    f32x4 acc[2][NF];
#pragma unroll
    for (int mi = 0; mi < 2; ++mi)
#pragma unroll
        for (int ni = 0; ni < NF; ++ni)
            acc[mi][ni] = (f32x4){0.f, 0.f, 0.f, 0.f};

    for (int k0 = 0; k0 < K; k0 += 32) {
        const int pos = k0 / IC;
        const int icb = k0 - pos * IC;
        const int ky = pos / KW, kx = pos - ky * KW;
        const long aoff = ((long)ky * IW + kx) * IC + icb;

        __syncthreads();
        {
            const uint4* src = (const uint4*)(abase + aoff);
            uint4 v0 = src[0], v1 = src[1];
            uint4* dst = (uint4*)(As + r * 40 + h * 16);
            dst[0] = v0; dst[1] = v1;
        }
        __syncthreads();

        bf16x8 af[2], bf[NF];
#pragma unroll
        for (int mi = 0; mi < 2; ++mi)
            af[mi] = *(const bf16x8*)(As + (wave * 32 + mi * 16 + l16) * 40 + quad * 8);
#pragma unroll
        for (int ni = 0; ni < NF; ++ni)
            bf[ni] = *(const bf16x8*)(Wp + (long)(ni * 16 + l16) * K + k0 + quad * 8);
#pragma unroll
        for (int mi = 0; mi < 2; ++mi)
#pragma unroll
            for (int ni = 0; ni < NF; ++ni)
                acc[mi][ni] = __builtin_amdgcn_mfma_f32_16x16x32_bf16(
                    af[mi], bf[ni], acc[mi][ni], 0, 0, 0);
    }

    const bool bf32 = getflag(bflag);
#pragma unroll
    for (int mi = 0; mi < 2; ++mi)
#pragma unroll
        for (int ni = 0; ni < NF; ++ni) {
            const int col = ni * 16 + l16;
            const float bv = ldin(bias, col, bf32);
#pragma unroll
            for (int rr = 0; rr < 4; ++rr) {
                const int row = m0 + wave * 32 + mi * 16 + quad * 4 + rr;
                if (row < Mtot)
                    outp[(long)row * OC + col] = f2b(fmaxf(acc[mi][ni][rr] + bv, 0.f));
            }
        }
}

// ---------------------------------------------------------------------------
// Split-K MFMA GEMM: C[M][N] f32 += A[M][K] bf16 * (B[N][K])^T bf16 over
// k-range [z*Kc, min(K,(z+1)*Kc)).  C must be pre-zeroed; atomicAdd epilogue.
// 128x128 tile, BK=32.  N % 128 == 0, Kc % 32 == 0.
// ---------------------------------------------------------------------------
#define LDSP 40
__global__ __launch_bounds__(256) void gemm_sk(
    const u16* __restrict__ A, const u16* __restrict__ B,
    float* __restrict__ C, int M, int N, int K, int Kc)
{
    __shared__ __attribute__((aligned(16))) u16 As[128 * LDSP];
    __shared__ __attribute__((aligned(16))) u16 Bs[128 * LDSP];

    const int tid  = threadIdx.x;
    const int wave = tid >> 6, lane = tid & 63;
    const int quad = lane >> 4, l16 = lane & 15;
    const int m0 = blockIdx.y * 128, n0 = blockIdx.x * 128;
    const int wm = (wave >> 1) * 64, wn = (wave & 1) * 64;
    const int kfrom = blockIdx.z * Kc;
    int kto = kfrom + Kc; if (kto > K) kto = K;

    f32x4 acc[4][4];
#pragma unroll
    for (int mi = 0; mi < 4; ++mi)
#pragma unroll
        for (int ni = 0; ni < 4; ++ni)
            acc[mi][ni] = (f32x4){0.f, 0.f, 0.f, 0.f};

    for (int k0 = kfrom; k0 < kto; k0 += 32) {
        __syncthreads();
#pragma unroll
        for (int pass = 0; pass < 2; ++pass) {
            int idx = tid + pass * 256;
            int r = idx >> 2, seg = idx & 3;
            int gr = m0 + r; if (gr > M - 1) gr = M - 1;
            uint4 va = *(const uint4*)(A + (long)gr * K + k0 + seg * 8);
            *(uint4*)(As + r * LDSP + seg * 8) = va;
            uint4 vb = *(const uint4*)(B + (long)(n0 + r) * K + k0 + seg * 8);
            *(uint4*)(Bs + r * LDSP + seg * 8) = vb;
        }
        __syncthreads();

        bf16x8 af[4], bfr[4];
#pragma unroll
        for (int mi = 0; mi < 4; ++mi)
            af[mi] = *(const bf16x8*)(As + (wm + mi * 16 + l16) * LDSP + quad * 8);
#pragma unroll
        for (int ni = 0; ni < 4; ++ni)
            bfr[ni] = *(const bf16x8*)(Bs + (wn + ni * 16 + l16) * LDSP + quad * 8);
#pragma unroll
        for (int mi = 0; mi < 4; ++mi)
#pragma unroll
            for (int ni = 0; ni < 4; ++ni)
                acc[mi][ni] = __builtin_amdgcn_mfma_f32_16x16x32_bf16(
                    af[mi], bfr[ni], acc[mi][ni], 0, 0, 0);
    }

#pragma unroll
    for (int mi = 0; mi < 4; ++mi)
#pragma unroll
        for (int ni = 0; ni < 4; ++ni) {
            int col = n0 + wn + ni * 16 + l16;
#pragma unroll
            for (int rr = 0; rr < 4; ++rr) {
                int row = m0 + wm + mi * 16 + quad * 4 + rr;
                if (row < M) atomicAdd(&C[(long)row * N + col], acc[mi][ni][rr]);
            }
        }
}

// ---------------------------------------------------------------------------
// Weight packing kernels (f32/bf16-flagged source -> bf16 dest).
// ---------------------------------------------------------------------------
__global__ __launch_bounds__(256) void pack_bf16(
    const void* __restrict__ src, const int* flag, u16* __restrict__ dst, long n)
{
    long idx = (long)blockIdx.x * 256 + threadIdx.x;
    if (idx < n) dst[idx] = f2b(ldin(src, idx, getflag(flag)));
}

// W2 OIHW [64][32][4][4] -> [oc][(ky*4+kx)*32 + ic]
__global__ __launch_bounds__(256) void pack_w2(
    const void* __restrict__ src, const int* flag, u16* __restrict__ dst)
{
    int idx = blockIdx.x * 256 + threadIdx.x;
    if (idx >= 64 * 512) return;
    int oc = idx >> 9, kk = idx & 511;
    int pos = kk >> 5, ic = kk & 31;
    int ky = pos >> 2, kx = pos & 3;
    dst[idx] = f2b(ldin(src, ((long)(oc * 32 + ic) * 4 + ky) * 4 + kx, getflag(flag)));
}

// W3 OIHW [64][64][3][3] -> [oc][(ky*3+kx)*64 + ic]
__global__ __launch_bounds__(256) void pack_w3(
    const void* __restrict__ src, const int* flag, u16* __restrict__ dst)
{
    int idx = blockIdx.x * 256 + threadIdx.x;
    if (idx >= 64 * 576) return;
    int oc = idx / 576, kk = idx % 576;
    int pos = kk >> 6, ic = kk & 63;
    int ky = pos / 3, kx = pos % 3;
    dst[idx] = f2b(ldin(src, ((long)(oc * 64 + ic) * 3 + ky) * 3 + kx, getflag(flag)));
}

// Wl [512][3136] (k = oc*49 + p) -> [n][p*64 + oc]  (matches NHWC-flat c3)
__global__ __launch_bounds__(256) void pack_wl(
    const void* __restrict__ src, const int* flag, u16* __restrict__ dst)
{
    int idx = blockIdx.x * 256 + threadIdx.x;
    if (idx >= 512 * 3136) return;
    int n = idx / 3136, kk = idx % 3136;
    int p = kk >> 6, oc = kk & 63;
    dst[idx] = f2b(ldin(src, (long)n * 3136 + oc * 49 + p, getflag(flag)));
}

__global__ __launch_bounds__(256) void pack_bcat(
    const void* __restrict__ Wih, const void* __restrict__ Whh,
    const int* flag, u16* __restrict__ Bcat)
{
    int idx = blockIdx.x * 256 + threadIdx.x;
    if (idx >= 512 * 640) return;
    const bool f32 = getflag(flag);
    int n = idx / 640, k = idx % 640;
    Bcat[idx] = f2b((k < 512) ? ldin(Wih, n * 512 + k, f32)
                              : ldin(Whh, n * 128 + (k - 512), f32));
}

// ---------------------------------------------------------------------------
// bias + ReLU + LayerNorm over 512 features, per row.  Writes f32 to d_out.
// ---------------------------------------------------------------------------
__global__ __launch_bounds__(256) void ln_relu(
    const float* __restrict__ y,
    const void* __restrict__ bias, const void* __restrict__ g,
    const void* __restrict__ be, const int* flag,
    float* __restrict__ outv)
{
    __shared__ float red[256];
    __shared__ float mean_s, inv_s;

    const int b = blockIdx.x, tid = threadIdx.x;
    const bool f32 = getflag(flag);
    const float* yr = y + (long)b * 512;

    float v0 = fmaxf(yr[tid]       + ldin(bias, tid,       f32), 0.f);
    float v1 = fmaxf(yr[tid + 256] + ldin(bias, tid + 256, f32), 0.f);

    red[tid] = v0 + v1;
    __syncthreads();
    for (int s = 128; s > 0; s >>= 1) { if (tid < s) red[tid] += red[tid + s]; __syncthreads(); }
    if (tid == 0) mean_s = red[0] * (1.f / 512.f);
    __syncthreads();
    float mean = mean_s;
    float d0 = v0 - mean, d1 = v1 - mean;
    red[tid] = d0 * d0 + d1 * d1;
    __syncthreads();
    for (int s = 128; s > 0; s >>= 1) { if (tid < s) red[tid] += red[tid + s]; __syncthreads(); }
    if (tid == 0) inv_s = rsqrtf(red[0] * (1.f / 512.f) + 1e-5f);
    __syncthreads();
    float inv = inv_s;

    outv[(long)b * 512 + tid]       = d0 * inv * ldin(g, tid,       f32) + ldin(be, tid,       f32);
    outv[(long)b * 512 + tid + 256] = d1 * inv * ldin(g, tid + 256, f32) + ldin(be, tid + 256, f32);
}

// ---------------------------------------------------------------------------
// Attention gating -> Acat row = [fused (512) | (1-done)*h0 (128)] bf16.
// ---------------------------------------------------------------------------
__global__ __launch_bounds__(256) void attn_fuse(
    const float* __restrict__ vff, const float* __restrict__ aff,
    const void* __restrict__ h0, const void* __restrict__ done,
    const void* __restrict__ avW, const void* __restrict__ avb,
    const void* __restrict__ aaW, const void* __restrict__ aab,
    const void* __restrict__ asW, const void* __restrict__ asb,
    const void* __restrict__ attW, const void* __restrict__ attb,
    const int* flag, u16* __restrict__ Acat)
{
    __shared__ float vs[512], afs[512], hs[128], part[8][32], act[32], wsm[2];
    const int b = blockIdx.x, tid = threadIdx.x;
    const bool f32 = getflag(flag);

    for (int i = tid; i < 512; i += 256) {
        vs[i]  = vff[(long)b * 512 + i];
        afs[i] = aff[(long)b * 512 + i];
    }
    if (tid < 128) hs[tid] = ldin(h0, b * 128 + tid, f32);
    __syncthreads();

    {
        const int j = tid & 31, g = tid >> 5;
        float a = 0.f;
        for (int k = g * 64; k < g * 64 + 64; ++k)
            a += vs[k] * ldin(avW, j * 512 + k, f32) + afs[k] * ldin(aaW, j * 512 + k, f32);
        for (int k = g * 16; k < g * 16 + 16; ++k)
            a += hs[k] * ldin(asW, j * 128 + k, f32);
        part[g][j] = a;
    }
    __syncthreads();
    if (tid < 32) {
        float a = ldin(avb, tid, f32) + ldin(aab, tid, f32) + ldin(asb, tid, f32);
#pragma unroll
        for (int g2 = 0; g2 < 8; ++g2) a += part[g2][tid];
        act[tid] = tanhf(a);
    }
    __syncthreads();
    if (tid == 0) {
        float l0 = ldin(attb, 0, f32), l1 = ldin(attb, 1, f32);
        for (int j = 0; j < 32; ++j) {
            l0 += act[j] * ldin(attW, j, f32);
            l1 += act[j] * ldin(attW, 32 + j, f32);
        }
        float mx = fmaxf(l0, l1);
        float e0 = expf(l0 - mx), e1 = expf(l1 - mx);
        float s = e0 + e1;
        wsm[0] = e0 / s; wsm[1] = e1 / s;
    }
    __syncthreads();
    const float w0 = wsm[0], w1 = wsm[1];
    const float m = 1.f - ldin(done, b, f32);
    for (int i = tid; i < 512; i += 256)
        Acat[(long)b * 640 + i] = f2b(w0 * vs[i] + w1 * afs[i]);
    if (tid < 128)
        Acat[(long)b * 640 + 512 + tid] = f2b(m * hs[tid]);
}

// ---------------------------------------------------------------------------
// LSTM pointwise epilogue (gate order i,f,g,o).  Writes f32 h_new, c_new.
// ---------------------------------------------------------------------------
__global__ __launch_bounds__(128) void lstm_fin(
    const float* __restrict__ gates,
    const void* __restrict__ bih, const void* __restrict__ bhh,
    const void* __restrict__ c0, const void* __restrict__ done,
    const int* flag, float* __restrict__ out)
{
    const int b = blockIdx.x, j = threadIdx.x;
    const bool f32 = getflag(flag);
    const float* G = gates + (long)b * 512;
    float gi = G[j]       + ldin(bih, j,       f32) + ldin(bhh, j,       f32);
    float gf = G[128 + j] + ldin(bih, 128 + j, f32) + ldin(bhh, 128 + j, f32);
    float gg = G[256 + j] + ldin(bih, 256 + j, f32) + ldin(bhh, 256 + j, f32);
    float go = G[384 + j] + ldin(bih, 384 + j, f32) + ldin(bhh, 384 + j, f32);
    float m  = 1.f - ldin(done, b, f32);
    float c  = m * ldin(c0, b * 128 + j, f32);
    float si = 1.f / (1.f + expf(-gi));
    float sf = 1.f / (1.f + expf(-gf));
    float so = 1.f / (1.f + expf(-go));
    float cn = sf * c + si * tanhf(gg);
    float hn = so * tanhf(cn);
    out[b * 128 + j]          = hn;
    out[131072 + b * 128 + j] = cn;
}

// ---------------------------------------------------------------------------
extern "C" void kernel_launch(void* const* d_in, const int* in_sizes, int n_in,
                              void* d_out, int out_size, void* d_ws, size_t ws_size,
                              hipStream_t stream)
{
    (void)in_sizes; (void)n_in; (void)out_size;

    const void* x     = d_in[0];
    const void* done  = d_in[1];
    const void* h0    = d_in[2];
    const void* c0in  = d_in[3];
    const void* vW1   = d_in[4];
    const void* vb1   = d_in[5];
    const void* vW2   = d_in[6];
    const void* vb2   = d_in[7];
    const void* vW3   = d_in[8];
    const void* vb3   = d_in[9];
    const void* vWl   = d_in[10];
    const void* vbl   = d_in[11];
    const void* aW1   = d_in[12];
    const void* ab1   = d_in[13];
    const void* aW2   = d_in[14];
    const void* ab2   = d_in[15];
    const void* aW3   = d_in[16];
    const void* ab3   = d_in[17];
    const void* aWl   = d_in[18];
    const void* abl   = d_in[19];
    const void* vln_g = d_in[20];
    const void* vln_b = d_in[21];
    const void* aln_g = d_in[22];
    const void* aln_b = d_in[23];
    const void* att_vW = d_in[24];
    const void* att_vb = d_in[25];
    const void* att_aW = d_in[26];
    const void* att_ab = d_in[27];
    const void* att_sW = d_in[28];
    const void* att_sb = d_in[29];
    const void* attW  = d_in[30];
    const void* attb  = d_in[31];
    const void* Wih   = d_in[32];
    const void* Whh   = d_in[33];
    const void* bih   = d_in[34];
    const void* bhh   = d_in[35];

    float* out = (float*)d_out;
    float* vf_out = out + 262144;
    float* af_out = out + 786432;

    // ---- adaptive batch chunk ----
    const size_t PERBATCH = 12800ul * 2 + 5184ul * 2;          // c1 + c2 NHWC bf16
    const size_t PERSIST  = 16
        + 1024ul * 512 * 4       // gates
        + 1024ul * 512 * 4       // ych
        + 1024ul * 640 * 2       // Acat
        + 512ul * 640 * 2        // Bcat
        + 2ul * 512 * 3136 * 2   // Wlb
        + 2ul * 32 * 64 * 2      // Wp1
        + 2ul * 64 * 512 * 2     // Wp2
        + 2ul * 64 * 576 * 2     // Wp3
        + 1024ul * 3136 * 2;     // c3 full (one tower at a time)
    int NB = 64;
    const int cands[4] = {1024, 512, 256, 128};
    for (int i = 0; i < 4; ++i)
        if (PERSIST + (size_t)cands[i] * PERBATCH <= ws_size) { NB = cands[i]; break; }
    const int NC = 1024 / NB;

    // ---- workspace carve ----
    char* p = (char*)d_ws;
    int*   flag  = (int*)p;   p += 16;
    float* gates = (float*)p; p += 1024ul * 512 * 4;
    float* ych   = (float*)p; p += 1024ul * 512 * 4;
    u16*   Acat  = (u16*)p;   p += 1024ul * 640 * 2;
    u16*   Bcat  = (u16*)p;   p += 512ul * 640 * 2;
    u16*   Wlb   = (u16*)p;   p += 2ul * 512 * 3136 * 2;
    u16*   Wp1   = (u16*)p;   p += 2ul * 32 * 64 * 2;
    u16*   Wp2   = (u16*)p;   p += 2ul * 64 * 512 * 2;
    u16*   Wp3   = (u16*)p;   p += 2ul * 64 * 576 * 2;
    u16*   c3f   = (u16*)p;   p += 1024ul * 3136 * 2;
    u16*   c1    = (u16*)p;   p += (size_t)NB * 12800 * 2;
    u16*   c2    = (u16*)p;

    hipLaunchKernelGGL(sniff, dim3(1), dim3(256), 0, stream, (const u16*)x, flag);
    hipLaunchKernelGGL(pack_bcat, dim3(1280), dim3(256), 0, stream, Wih, Whh, flag, Bcat);
    hipLaunchKernelGGL(pack_bf16, dim3(8), dim3(256), 0, stream, vW1, flag, Wp1, 2048);
    hipLaunchKernelGGL(pack_bf16, dim3(8), dim3(256), 0, stream, aW1, flag, Wp1 + 2048, 2048);
    hipLaunchKernelGGL(pack_w2, dim3(128), dim3(256), 0, stream, vW2, flag, Wp2);
    hipLaunchKernelGGL(pack_w2, dim3(128), dim3(256), 0, stream, aW2, flag, Wp2 + 32768);
    hipLaunchKernelGGL(pack_w3, dim3(144), dim3(256), 0, stream, vW3, flag, Wp3);
    hipLaunchKernelGGL(pack_w3, dim3(144), dim3(256), 0, stream, aW3, flag, Wp3 + 36864);
    hipLaunchKernelGGL(pack_wl, dim3(6272), dim3(256), 0, stream, vWl, flag, Wlb);
    hipLaunchKernelGGL(pack_wl, dim3(6272), dim3(256), 0, stream, aWl, flag, Wlb + 512ul * 3136);

    for (int t = 0; t < 2; ++t) {
        const void* b1 = t ? ab1 : vb1;
        const void* b2 = t ? ab2 : vb2;
        const void* b3 = t ? ab3 : vb3;
        const void* bl = t ? abl : vbl;
        const void* lg = t ? aln_g : vln_g;
        const void* lb = t ? aln_b : vln_b;
        float* fout = t ? af_out : vf_out;

        for (int cch = 0; cch < NC; ++cch) {
            const int b0 = cch * NB;
            const int M1 = NB * 400, M2 = NB * 81, M3 = NB * 49;

            hipLaunchKernelGGL(conv1_mfma, dim3((M1 + 127) / 128), dim3(256), 0, stream,
                x, (long)b0 * 14112 + (long)t * 7056, flag,
                Wp1 + t * 2048, b1, flag, c1, M1);

            hipLaunchKernelGGL((convN_mfma<32, 20, 20, 64, 4, 4, 2, 9, 9>),
                dim3((M2 + 127) / 128), dim3(256), 0, stream,
                c1, Wp2 + t * 32768, b2, flag, c2, M2);

            hipLaunchKernelGGL((convN_mfma<64, 9, 9, 64, 3, 3, 1, 7, 7>),
                dim3((M3 + 127) / 128), dim3(256), 0, stream,
                c2, Wp3 + t * 36864, b3, flag, c3f + (long)b0 * 3136, M3);
        }

        hipLaunchKernelGGL(zero_f32, dim3(2048), dim3(256), 0, stream, ych, 1024l * 512);
        // ych = c3f @ Wlb[t]^T   M=1024 N=512 K=3136, split-K 7 (Kc=448)
        hipLaunchKernelGGL(gemm_sk, dim3(4, 8, 7), dim3(256), 0, stream,
            c3f, Wlb + (size_t)t * 512 * 3136, ych, 1024, 512, 3136, 448);

        hipLaunchKernelGGL(ln_relu, dim3(1024), dim3(256), 0, stream,
            ych, bl, lg, lb, flag, fout);
    }

    hipLaunchKernelGGL(attn_fuse, dim3(1024), dim3(256), 0, stream,
        vf_out, af_out, h0, done,
        att_vW, att_vb, att_aW, att_ab, att_sW, att_sb, attW, attb, flag, Acat);

    hipLaunchKernelGGL(zero_f32, dim3(2048), dim3(256), 0, stream, gates, 1024l * 512);
    // gates = Acat @ Bcat^T   M=1024 N=512 K=640, split-K 4 (Kc=160)
    hipLaunchKernelGGL(gemm_sk, dim3(4, 8, 4), dim3(256), 0, stream,
        Acat, Bcat, gates, 1024, 512, 640, 160);

    hipLaunchKernelGGL(lstm_fin, dim3(1024), dim3(128), 0, stream,
        gates, bih, bhh, c0in, done, flag, out);
}

// Round 7
// 488.505 us; speedup vs baseline: 5.2858x; 1.2283x over previous
//
#include <hip/hip_runtime.h>

// ---------------------------------------------------------------------------
// AlignableCaslAgent forward.  Inputs f32 (flag-verified), outputs f32.
// Round 6: attention weights transpose-packed to [1152][32] bf16 so attn_fuse
// weight reads are lane-coalesced (was 129 us latency-bound, VALUBusy 2%);
// pack_wl rewritten as LDS row-transpose (coalesced reads AND writes).
// ---------------------------------------------------------------------------

typedef unsigned short u16;
typedef unsigned int u32;
typedef __attribute__((ext_vector_type(8))) short bf16x8;
typedef __attribute__((ext_vector_type(4))) float f32x4;

__device__ __forceinline__ float b2f(u16 u) {
    union { u32 i; float f; } v; v.i = ((u32)u) << 16; return v.f;
}
__device__ __forceinline__ u16 f2b(float f) {
    union { float f; u32 i; } v; v.f = f;
    u32 r = v.i + 0x7fffu + ((v.i >> 16) & 1u);
    return (u16)(r >> 16);
}
__device__ __forceinline__ float ldin(const void* p, long i, bool f32) {
    return f32 ? ((const float*)p)[i] : b2f(((const u16*)p)[i]);
}
__device__ __forceinline__ bool getflag(const int* f) {
    return f != nullptr && *f != 0;
}

// ---------------------------------------------------------------------------
__global__ __launch_bounds__(256) void sniff(const u16* __restrict__ x, int* flag)
{
    __shared__ int s;
    if (threadIdx.x == 0) s = 0;
    __syncthreads();
    int hit = 0;
    for (int i = threadIdx.x; i < 16384; i += 256) {
        int e = (x[i] >> 7) & 0xFF;
        if (e >= 0x90) hit = 1;
    }
    if (hit) atomicOr(&s, 1);
    __syncthreads();
    if (threadIdx.x == 0) *flag = s;
}

__global__ __launch_bounds__(256) void zero_f32(float* __restrict__ p, long n)
{
    long i = (long)blockIdx.x * 256 + threadIdx.x;
    if (i < n) p[i] = 0.f;
}

// ---------------------------------------------------------------------------
// conv1 as implicit-im2col MFMA (unchanged from round 5).
// ---------------------------------------------------------------------------
__global__ __launch_bounds__(256) void conv1_mfma(
    const void* __restrict__ in_all, long in_off, const int* inflag,
    const u16* __restrict__ Wp,          // [32][64] bf16
    const void* __restrict__ bias, const int* bflag,
    u16* __restrict__ outp, int Mtot)
{
    __shared__ __attribute__((aligned(16))) u16 As[128 * 40];

    const int tid = threadIdx.x;
    const int wave = tid >> 6, lane = tid & 63, quad = lane >> 4, l16 = lane & 15;
    const int m0 = blockIdx.x * 128;
    const bool inf32 = getflag(inflag);

    const int r = tid >> 1, h = tid & 1;
    int m = m0 + r; if (m > Mtot - 1) m = Mtot - 1;
    const int b = m / 400, p = m % 400;
    const int oy = p / 20, ox = p % 20;
    const long fbase = in_off + (long)b * 14112 + (long)(oy * 4) * 84 + ox * 4;

    f32x4 acc[2][2];
#pragma unroll
    for (int mi = 0; mi < 2; ++mi)
#pragma unroll
        for (int ni = 0; ni < 2; ++ni)
            acc[mi][ni] = (f32x4){0.f, 0.f, 0.f, 0.f};

#pragma unroll
    for (int ks = 0; ks < 2; ++ks) {
        const int k0 = ks * 32;
        __syncthreads();
        {
            u16 tmp[16];
            const int kbase = k0 + h * 16;
            if (inf32) {
                const float* F = (const float*)in_all + fbase;
#pragma unroll
                for (int rr = 0; rr < 2; ++rr) {
                    const int ky = (kbase >> 3) + rr;
                    float4 v0 = *(const float4*)(F + ky * 84);
                    float4 v1 = *(const float4*)(F + ky * 84 + 4);
                    tmp[rr * 8 + 0] = f2b(v0.x); tmp[rr * 8 + 1] = f2b(v0.y);
                    tmp[rr * 8 + 2] = f2b(v0.z); tmp[rr * 8 + 3] = f2b(v0.w);
                    tmp[rr * 8 + 4] = f2b(v1.x); tmp[rr * 8 + 5] = f2b(v1.y);
                    tmp[rr * 8 + 6] = f2b(v1.z); tmp[rr * 8 + 7] = f2b(v1.w);
                }
            } else {
                const u16* F = (const u16*)in_all + fbase;
#pragma unroll
                for (int j = 0; j < 16; ++j) {
                    const int k = kbase + j;
                    tmp[j] = F[(k >> 3) * 84 + (k & 7)];
                }
            }
            uint4* dst = (uint4*)(As + r * 40 + h * 16);
            dst[0] = ((const uint4*)tmp)[0];
            dst[1] = ((const uint4*)tmp)[1];
        }
        __syncthreads();

        bf16x8 af[2], bf[2];
#pragma unroll
        for (int mi = 0; mi < 2; ++mi)
            af[mi] = *(const bf16x8*)(As + (wave * 32 + mi * 16 + l16) * 40 + quad * 8);
#pragma unroll
        for (int ni = 0; ni < 2; ++ni)
            bf[ni] = *(const bf16x8*)(Wp + (ni * 16 + l16) * 64 + k0 + quad * 8);
#pragma unroll
        for (int mi = 0; mi < 2; ++mi)
#pragma unroll
            for (int ni = 0; ni < 2; ++ni)
                acc[mi][ni] = __builtin_amdgcn_mfma_f32_16x16x32_bf16(
                    af[mi], bf[ni], acc[mi][ni], 0, 0, 0);
    }

    const bool bf32 = getflag(bflag);
#pragma unroll
    for (int mi = 0; mi < 2; ++mi)
#pragma unroll
        for (int ni = 0; ni < 2; ++ni) {
            const int col = ni * 16 + l16;
            const float bv = ldin(bias, col, bf32);
#pragma unroll
            for (int rr = 0; rr < 4; ++rr) {
                const int row = m0 + wave * 32 + mi * 16 + quad * 4 + rr;
                if (row < Mtot)
                    outp[(long)row * 32 + col] = f2b(fmaxf(acc[mi][ni][rr] + bv, 0.f));
            }
        }
}

// ---------------------------------------------------------------------------
// Generic NHWC bf16 conv as implicit-im2col MFMA (unchanged).
// ---------------------------------------------------------------------------
template<int IC, int IH, int IW, int OC, int KH, int KW, int S, int OH, int OW>
__global__ __launch_bounds__(256) void convN_mfma(
    const u16* __restrict__ in, const u16* __restrict__ Wp,
    const void* __restrict__ bias, const int* bflag,
    u16* __restrict__ outp, int Mtot)
{
    constexpr int OP = OH * OW;
    constexpr int K  = KH * KW * IC;
    constexpr int NF = OC / 16;

    __shared__ __attribute__((aligned(16))) u16 As[128 * 40];

    const int tid = threadIdx.x;
    const int wave = tid >> 6, lane = tid & 63, quad = lane >> 4, l16 = lane & 15;
    const int m0 = blockIdx.x * 128;

    const int r = tid >> 1, h = tid & 1;
    int m = m0 + r; if (m > Mtot - 1) m = Mtot - 1;
    const int b = m / OP, p = m % OP;
    const int oy = p / OW, ox = p % OW;
    const u16* abase = in + (((long)b * IH + oy * S) * IW + ox * S) * IC + h * 16;

    f32x4 acc[2][NF];
#pragma unroll
    for (int mi = 0; mi < 2; ++mi)
#pragma unroll
        for (int ni = 0; ni < NF; ++ni)
            acc[mi][ni] = (f32x4){0.f, 0.f, 0.f, 0.f};

    for (int k0 = 0; k0 < K; k0 += 32) {
        const int pos = k0 / IC;
        const int icb = k0 - pos * IC;
        const int ky = pos / KW, kx = pos - ky * KW;
        const long aoff = ((long)ky * IW + kx) * IC + icb;

        __syncthreads();
        {
            const uint4* src = (const uint4*)(abase + aoff);
            uint4 v0 = src[0], v1 = src[1];
            uint4* dst = (uint4*)(As + r * 40 + h * 16);
            dst[0] = v0; dst[1] = v1;
        }
        __syncthreads();

        bf16x8 af[2], bf[NF];
#pragma unroll
        for (int mi = 0; mi < 2; ++mi)
            af[mi] = *(const bf16x8*)(As + (wave * 32 + mi * 16 + l16) * 40 + quad * 8);
#pragma unroll
        for (int ni = 0; ni < NF; ++ni)
            bf[ni] = *(const bf16x8*)(Wp + (long)(ni * 16 + l16) * K + k0 + quad * 8);
#pragma unroll
        for (int mi = 0; mi < 2; ++mi)
#pragma unroll
            for (int ni = 0; ni < NF; ++ni)
                acc[mi][ni] = __builtin_amdgcn_mfma_f32_16x16x32_bf16(
                    af[mi], bf[ni], acc[mi][ni], 0, 0, 0);
    }

    const bool bf32 = getflag(bflag);
#pragma unroll
    for (int mi = 0; mi < 2; ++mi)
#pragma unroll
        for (int ni = 0; ni < NF; ++ni) {
            const int col = ni * 16 + l16;
            const float bv = ldin(bias, col, bf32);
#pragma unroll
            for (int rr = 0; rr < 4; ++rr) {
                const int row = m0 + wave * 32 + mi * 16 + quad * 4 + rr;
                if (row < Mtot)
                    outp[(long)row * OC + col] = f2b(fmaxf(acc[mi][ni][rr] + bv, 0.f));
            }
        }
}

// ---------------------------------------------------------------------------
// Split-K MFMA GEMM (unchanged).
// ---------------------------------------------------------------------------
#define LDSP 40
__global__ __launch_bounds__(256) void gemm_sk(
    const u16* __restrict__ A, const u16* __restrict__ B,
    float* __restrict__ C, int M, int N, int K, int Kc)
{
    __shared__ __attribute__((aligned(16))) u16 As[128 * LDSP];
    __shared__ __attribute__((aligned(16))) u16 Bs[128 * LDSP];

    const int tid  = threadIdx.x;
    const int wave = tid >> 6, lane = tid & 63;
    const int quad = lane >> 4, l16 = lane & 15;
    const int m0 = blockIdx.y * 128, n0 = blockIdx.x * 128;
    const int wm = (wave >> 1) * 64, wn = (wave & 1) * 64;
    const int kfrom = blockIdx.z * Kc;
    int kto = kfrom + Kc; if (kto > K) kto = K;

    f32x4 acc[4][4];
#pragma unroll
    for (int mi = 0; mi < 4; ++mi)
#pragma unroll
        for (int ni = 0; ni < 4; ++ni)
            acc[mi][ni] = (f32x4){0.f, 0.f, 0.f, 0.f};

    for (int k0 = kfrom; k0 < kto; k0 += 32) {
        __syncthreads();
#pragma unroll
        for (int pass = 0; pass < 2; ++pass) {
            int idx = tid + pass * 256;
            int r = idx >> 2, seg = idx & 3;
            int gr = m0 + r; if (gr > M - 1) gr = M - 1;
            uint4 va = *(const uint4*)(A + (long)gr * K + k0 + seg * 8);
            *(uint4*)(As + r * LDSP + seg * 8) = va;
            uint4 vb = *(const uint4*)(B + (long)(n0 + r) * K + k0 + seg * 8);
            *(uint4*)(Bs + r * LDSP + seg * 8) = vb;
        }
        __syncthreads();

        bf16x8 af[4], bfr[4];
#pragma unroll
        for (int mi = 0; mi < 4; ++mi)
            af[mi] = *(const bf16x8*)(As + (wm + mi * 16 + l16) * LDSP + quad * 8);
#pragma unroll
        for (int ni = 0; ni < 4; ++ni)
            bfr[ni] = *(const bf16x8*)(Bs + (wn + ni * 16 + l16) * LDSP + quad * 8);
#pragma unroll
        for (int mi = 0; mi < 4; ++mi)
#pragma unroll
            for (int ni = 0; ni < 4; ++ni)
                acc[mi][ni] = __builtin_amdgcn_mfma_f32_16x16x32_bf16(
                    af[mi], bfr[ni], acc[mi][ni], 0, 0, 0);
    }

#pragma unroll
    for (int mi = 0; mi < 4; ++mi)
#pragma unroll
        for (int ni = 0; ni < 4; ++ni) {
            int col = n0 + wn + ni * 16 + l16;
#pragma unroll
            for (int rr = 0; rr < 4; ++rr) {
                int row = m0 + wm + mi * 16 + quad * 4 + rr;
                if (row < M) atomicAdd(&C[(long)row * N + col], acc[mi][ni][rr]);
            }
        }
}

// ---------------------------------------------------------------------------
// Weight packing kernels.
// ---------------------------------------------------------------------------
__global__ __launch_bounds__(256) void pack_bf16(
    const void* __restrict__ src, const int* flag, u16* __restrict__ dst, long n)
{
    long idx = (long)blockIdx.x * 256 + threadIdx.x;
    if (idx < n) dst[idx] = f2b(ldin(src, idx, getflag(flag)));
}

// W2 OIHW [64][32][4][4] -> [oc][(ky*4+kx)*32 + ic]
__global__ __launch_bounds__(256) void pack_w2(
    const void* __restrict__ src, const int* flag, u16* __restrict__ dst)
{
    int idx = blockIdx.x * 256 + threadIdx.x;
    if (idx >= 64 * 512) return;
    int oc = idx >> 9, kk = idx & 511;
    int pos = kk >> 5, ic = kk & 31;
    int ky = pos >> 2, kx = pos & 3;
    dst[idx] = f2b(ldin(src, ((long)(oc * 32 + ic) * 4 + ky) * 4 + kx, getflag(flag)));
}

// W3 OIHW [64][64][3][3] -> [oc][(ky*3+kx)*64 + ic]
__global__ __launch_bounds__(256) void pack_w3(
    const void* __restrict__ src, const int* flag, u16* __restrict__ dst)
{
    int idx = blockIdx.x * 256 + threadIdx.x;
    if (idx >= 64 * 576) return;
    int oc = idx / 576, kk = idx % 576;
    int pos = kk >> 6, ic = kk & 63;
    int ky = pos / 3, kx = pos % 3;
    dst[idx] = f2b(ldin(src, ((long)(oc * 64 + ic) * 3 + ky) * 3 + kx, getflag(flag)));
}

// Wl [512][3136] (k = oc*49 + p) -> [n][p*64 + oc], LDS row transpose:
// coalesced global reads AND writes; LDS gather stride 49*4B (odd) = 2-way.
__global__ __launch_bounds__(256) void pack_wl(
    const void* __restrict__ src, const int* flag, u16* __restrict__ dst)
{
    __shared__ float row[3136];
    const int n = blockIdx.x, tid = threadIdx.x;
    const bool f32 = getflag(flag);
    for (int i = tid; i < 3136; i += 256)
        row[i] = ldin(src, (long)n * 3136 + i, f32);
    __syncthreads();
    for (int i = tid; i < 3136; i += 256) {
        int p = i >> 6, oc = i & 63;
        dst[(long)n * 3136 + i] = f2b(row[oc * 49 + p]);
    }
}

// Attention weights -> WT[1152][32] bf16: rows 0..511 avW^T, 512..1023 aaW^T,
// 1024..1151 asW^T.  One-time scatter-read, tiny (36K elems).
__global__ __launch_bounds__(256) void pack_attw(
    const void* __restrict__ avW, const void* __restrict__ aaW,
    const void* __restrict__ asW, const int* flag, u16* __restrict__ dst)
{
    int idx = blockIdx.x * 256 + threadIdx.x;
    if (idx >= 1152 * 32) return;
    const bool f32 = getflag(flag);
    int k = idx >> 5, j = idx & 31;
    float v;
    if (k < 512)       v = ldin(avW, (long)j * 512 + k, f32);
    else if (k < 1024) v = ldin(aaW, (long)j * 512 + (k - 512), f32);
    else               v = ldin(asW, (long)j * 128 + (k - 1024), f32);
    dst[idx] = f2b(v);
}

__global__ __launch_bounds__(256) void pack_bcat(
    const void* __restrict__ Wih, const void* __restrict__ Whh,
    const int* flag, u16* __restrict__ Bcat)
{
    int idx = blockIdx.x * 256 + threadIdx.x;
    if (idx >= 512 * 640) return;
    const bool f32 = getflag(flag);
    int n = idx / 640, k = idx % 640;
    Bcat[idx] = f2b((k < 512) ? ldin(Wih, n * 512 + k, f32)
                              : ldin(Whh, n * 128 + (k - 512), f32));
}

// ---------------------------------------------------------------------------
// bias + ReLU + LayerNorm over 512 features, per row (unchanged).
// ---------------------------------------------------------------------------
__global__ __launch_bounds__(256) void ln_relu(
    const float* __restrict__ y,
    const void* __restrict__ bias, const void* __restrict__ g,
    const void* __restrict__ be, const int* flag,
    float* __restrict__ outv)
{
    __shared__ float red[256];
    __shared__ float mean_s, inv_s;

    const int b = blockIdx.x, tid = threadIdx.x;
    const bool f32 = getflag(flag);
    const float* yr = y + (long)b * 512;

    float v0 = fmaxf(yr[tid]       + ldin(bias, tid,       f32), 0.f);
    float v1 = fmaxf(yr[tid + 256] + ldin(bias, tid + 256, f32), 0.f);

    red[tid] = v0 + v1;
    __syncthreads();
    for (int s = 128; s > 0; s >>= 1) { if (tid < s) red[tid] += red[tid + s]; __syncthreads(); }
    if (tid == 0) mean_s = red[0] * (1.f / 512.f);
    __syncthreads();
    float mean = mean_s;
    float d0 = v0 - mean, d1 = v1 - mean;
    red[tid] = d0 * d0 + d1 * d1;
    __syncthreads();
    for (int s = 128; s > 0; s >>= 1) { if (tid < s) red[tid] += red[tid + s]; __syncthreads(); }
    if (tid == 0) inv_s = rsqrtf(red[0] * (1.f / 512.f) + 1e-5f);
    __syncthreads();
    float inv = inv_s;

    outv[(long)b * 512 + tid]       = d0 * inv * ldin(g, tid,       f32) + ldin(be, tid,       f32);
    outv[(long)b * 512 + tid + 256] = d1 * inv * ldin(g, tid + 256, f32) + ldin(be, tid + 256, f32);
}

// ---------------------------------------------------------------------------
// Attention gating -> Acat row = [fused (512) | (1-done)*h0 (128)] bf16.
// Weight reads via transposed WT[1152][32]: lane j=tid&31 -> consecutive
// addresses -> coalesced.  Thread (g=tid>>5) owns a K-slice; LDS reduce.
// ---------------------------------------------------------------------------
__global__ __launch_bounds__(256) void attn_fuse(
    const float* __restrict__ vff, const float* __restrict__ aff,
    const void* __restrict__ h0, const void* __restrict__ done,
    const u16* __restrict__ WT,
    const void* __restrict__ avb, const void* __restrict__ aab,
    const void* __restrict__ asb,
    const void* __restrict__ attW, const void* __restrict__ attb,
    const int* flag, u16* __restrict__ Acat)
{
    __shared__ float vs[512], afs[512], hs[128], part[8][32], act[32], wsm[2];
    const int b = blockIdx.x, tid = threadIdx.x;
    const bool f32 = getflag(flag);

    for (int i = tid; i < 512; i += 256) {
        vs[i]  = vff[(long)b * 512 + i];
        afs[i] = aff[(long)b * 512 + i];
    }
    if (tid < 128) hs[tid] = ldin(h0, b * 128 + tid, f32);
    __syncthreads();

    {
        const int j = tid & 31, g = tid >> 5;
        float a = 0.f;
#pragma unroll 8
        for (int k = g * 64; k < g * 64 + 64; ++k)
            a += vs[k] * b2f(WT[k * 32 + j]);
#pragma unroll 8
        for (int k = g * 64; k < g * 64 + 64; ++k)
            a += afs[k] * b2f(WT[(512 + k) * 32 + j]);
#pragma unroll 8
        for (int k = g * 16; k < g * 16 + 16; ++k)
            a += hs[k] * b2f(WT[(1024 + k) * 32 + j]);
        part[g][j] = a;
    }
    __syncthreads();
    if (tid < 32) {
        float a = ldin(avb, tid, f32) + ldin(aab, tid, f32) + ldin(asb, tid, f32);
#pragma unroll
        for (int g2 = 0; g2 < 8; ++g2) a += part[g2][tid];
        act[tid] = tanhf(a);
    }
    __syncthreads();
    if (tid == 0) {
        float l0 = ldin(attb, 0, f32), l1 = ldin(attb, 1, f32);
        for (int j = 0; j < 32; ++j) {
            l0 += act[j] * ldin(attW, j, f32);
            l1 += act[j] * ldin(attW, 32 + j, f32);
        }
        float mx = fmaxf(l0, l1);
        float e0 = expf(l0 - mx), e1 = expf(l1 - mx);
        float s = e0 + e1;
        wsm[0] = e0 / s; wsm[1] = e1 / s;
    }
    __syncthreads();
    const float w0 = wsm[0], w1 = wsm[1];
    const float m = 1.f - ldin(done, b, f32);
    for (int i = tid; i < 512; i += 256)
        Acat[(long)b * 640 + i] = f2b(w0 * vs[i] + w1 * afs[i]);
    if (tid < 128)
        Acat[(long)b * 640 + 512 + tid] = f2b(m * hs[tid]);
}

// ---------------------------------------------------------------------------
// LSTM pointwise epilogue (unchanged).
// ---------------------------------------------------------------------------
__global__ __launch_bounds__(128) void lstm_fin(
    const float* __restrict__ gates,
    const void* __restrict__ bih, const void* __restrict__ bhh,
    const void* __restrict__ c0, const void* __restrict__ done,
    const int* flag, float* __restrict__ out)
{
    const int b = blockIdx.x, j = threadIdx.x;
    const bool f32 = getflag(flag);
    const float* G = gates + (long)b * 512;
    float gi = G[j]       + ldin(bih, j,       f32) + ldin(bhh, j,       f32);
    float gf = G[128 + j] + ldin(bih, 128 + j, f32) + ldin(bhh, 128 + j, f32);
    float gg = G[256 + j] + ldin(bih, 256 + j, f32) + ldin(bhh, 256 + j, f32);
    float go = G[384 + j] + ldin(bih, 384 + j, f32) + ldin(bhh, 384 + j, f32);
    float m  = 1.f - ldin(done, b, f32);
    float c  = m * ldin(c0, b * 128 + j, f32);
    float si = 1.f / (1.f + expf(-gi));
    float sf = 1.f / (1.f + expf(-gf));
    float so = 1.f / (1.f + expf(-go));
    float cn = sf * c + si * tanhf(gg);
    float hn = so * tanhf(cn);
    out[b * 128 + j]          = hn;
    out[131072 + b * 128 + j] = cn;
}

// ---------------------------------------------------------------------------
extern "C" void kernel_launch(void* const* d_in, const int* in_sizes, int n_in,
                              void* d_out, int out_size, void* d_ws, size_t ws_size,
                              hipStream_t stream)
{
    (void)in_sizes; (void)n_in; (void)out_size;

    const void* x     = d_in[0];
    const void* done  = d_in[1];
    const void* h0    = d_in[2];
    const void* c0in  = d_in[3];
    const void* vW1   = d_in[4];
    const void* vb1   = d_in[5];
    const void* vW2   = d_in[6];
    const void* vb2   = d_in[7];
    const void* vW3   = d_in[8];
    const void* vb3   = d_in[9];
    const void* vWl   = d_in[10];
    const void* vbl   = d_in[11];
    const void* aW1   = d_in[12];
    const void* ab1   = d_in[13];
    const void* aW2   = d_in[14];
    const void* ab2   = d_in[15];
    const void* aW3   = d_in[16];
    const void* ab3   = d_in[17];
    const void* aWl   = d_in[18];
    const void* abl   = d_in[19];
    const void* vln_g = d_in[20];
    const void* vln_b = d_in[21];
    const void* aln_g = d_in[22];
    const void* aln_b = d_in[23];
    const void* att_vW = d_in[24];
    const void* att_vb = d_in[25];
    const void* att_aW = d_in[26];
    const void* att_ab = d_in[27];
    const void* att_sW = d_in[28];
    const void* att_sb = d_in[29];
    const void* attW  = d_in[30];
    const void* attb  = d_in[31];
    const void* Wih   = d_in[32];
    const void* Whh   = d_in[33];
    const void* bih   = d_in[34];
    const void* bhh   = d_in[35];

    float* out = (float*)d_out;
    float* vf_out = out + 262144;
    float* af_out = out + 786432;

    // ---- adaptive batch chunk ----
    const size_t PERBATCH = 12800ul * 2 + 5184ul * 2;          // c1 + c2 NHWC bf16
    const size_t PERSIST  = 16
        + 1024ul * 512 * 4       // gates
        + 1024ul * 512 * 4       // ych
        + 1024ul * 640 * 2       // Acat
        + 512ul * 640 * 2        // Bcat
        + 2ul * 512 * 3136 * 2   // Wlb
        + 2ul * 32 * 64 * 2      // Wp1
        + 2ul * 64 * 512 * 2     // Wp2
        + 2ul * 64 * 576 * 2     // Wp3
        + 1152ul * 32 * 2        // WTatt
        + 1024ul * 3136 * 2;     // c3 full (one tower at a time)
    int NB = 64;
    const int cands[4] = {1024, 512, 256, 128};
    for (int i = 0; i < 4; ++i)
        if (PERSIST + (size_t)cands[i] * PERBATCH <= ws_size) { NB = cands[i]; break; }
    const int NC = 1024 / NB;

    // ---- workspace carve ----
    char* p = (char*)d_ws;
    int*   flag  = (int*)p;   p += 16;
    float* gates = (float*)p; p += 1024ul * 512 * 4;
    float* ych   = (float*)p; p += 1024ul * 512 * 4;
    u16*   Acat  = (u16*)p;   p += 1024ul * 640 * 2;
    u16*   Bcat  = (u16*)p;   p += 512ul * 640 * 2;
    u16*   Wlb   = (u16*)p;   p += 2ul * 512 * 3136 * 2;
    u16*   Wp1   = (u16*)p;   p += 2ul * 32 * 64 * 2;
    u16*   Wp2   = (u16*)p;   p += 2ul * 64 * 512 * 2;
    u16*   Wp3   = (u16*)p;   p += 2ul * 64 * 576 * 2;
    u16*   WTatt = (u16*)p;   p += 1152ul * 32 * 2;
    u16*   c3f   = (u16*)p;   p += 1024ul * 3136 * 2;
    u16*   c1    = (u16*)p;   p += (size_t)NB * 12800 * 2;
    u16*   c2    = (u16*)p;

    hipLaunchKernelGGL(sniff, dim3(1), dim3(256), 0, stream, (const u16*)x, flag);
    hipLaunchKernelGGL(pack_bcat, dim3(1280), dim3(256), 0, stream, Wih, Whh, flag, Bcat);
    hipLaunchKernelGGL(pack_bf16, dim3(8), dim3(256), 0, stream, vW1, flag, Wp1, 2048);
    hipLaunchKernelGGL(pack_bf16, dim3(8), dim3(256), 0, stream, aW1, flag, Wp1 + 2048, 2048);
    hipLaunchKernelGGL(pack_w2, dim3(128), dim3(256), 0, stream, vW2, flag, Wp2);
    hipLaunchKernelGGL(pack_w2, dim3(128), dim3(256), 0, stream, aW2, flag, Wp2 + 32768);
    hipLaunchKernelGGL(pack_w3, dim3(144), dim3(256), 0, stream, vW3, flag, Wp3);
    hipLaunchKernelGGL(pack_w3, dim3(144), dim3(256), 0, stream, aW3, flag, Wp3 + 36864);
    hipLaunchKernelGGL(pack_wl, dim3(512), dim3(256), 0, stream, vWl, flag, Wlb);
    hipLaunchKernelGGL(pack_wl, dim3(512), dim3(256), 0, stream, aWl, flag, Wlb + 512ul * 3136);
    hipLaunchKernelGGL(pack_attw, dim3(144), dim3(256), 0, stream,
        att_vW, att_aW, att_sW, flag, WTatt);

    for (int t = 0; t < 2; ++t) {
        const void* b1 = t ? ab1 : vb1;
        const void* b2 = t ? ab2 : vb2;
        const void* b3 = t ? ab3 : vb3;
        const void* bl = t ? abl : vbl;
        const void* lg = t ? aln_g : vln_g;
        const void* lb = t ? aln_b : vln_b;
        float* fout = t ? af_out : vf_out;

        for (int cch = 0; cch < NC; ++cch) {
            const int b0 = cch * NB;
            const int M1 = NB * 400, M2 = NB * 81, M3 = NB * 49;

            hipLaunchKernelGGL(conv1_mfma, dim3((M1 + 127) / 128), dim3(256), 0, stream,
                x, (long)b0 * 14112 + (long)t * 7056, flag,
                Wp1 + t * 2048, b1, flag, c1, M1);

            hipLaunchKernelGGL((convN_mfma<32, 20, 20, 64, 4, 4, 2, 9, 9>),
                dim3((M2 + 127) / 128), dim3(256), 0, stream,
                c1, Wp2 + t * 32768, b2, flag, c2, M2);

            hipLaunchKernelGGL((convN_mfma<64, 9, 9, 64, 3, 3, 1, 7, 7>),
                dim3((M3 + 127) / 128), dim3(256), 0, stream,
                c2, Wp3 + t * 36864, b3, flag, c3f + (long)b0 * 3136, M3);
        }

        hipLaunchKernelGGL(zero_f32, dim3(2048), dim3(256), 0, stream, ych, 1024l * 512);
        hipLaunchKernelGGL(gemm_sk, dim3(4, 8, 7), dim3(256), 0, stream,
            c3f, Wlb + (size_t)t * 512 * 3136, ych, 1024, 512, 3136, 448);

        hipLaunchKernelGGL(ln_relu, dim3(1024), dim3(256), 0, stream,
            ych, bl, lg, lb, flag, fout);
    }

    hipLaunchKernelGGL(attn_fuse, dim3(1024), dim3(256), 0, stream,
        vf_out, af_out, h0, done, WTatt,
        att_vb, att_ab, att_sb, attW, attb, flag, Acat);

    hipLaunchKernelGGL(zero_f32, dim3(2048), dim3(256), 0, stream, gates, 1024l * 512);
    hipLaunchKernelGGL(gemm_sk, dim3(4, 8, 4), dim3(256), 0, stream,
        Acat, Bcat, gates, 1024, 512, 640, 160);

    hipLaunchKernelGGL(lstm_fin, dim3(1024), dim3(128), 0, stream,
        gates, bih, bhh, c0in, done, flag, out);
}

// Round 8
// 377.434 us; speedup vs baseline: 6.8413x; 1.2943x over previous
//
#include <hip/hip_runtime.h>

// ---------------------------------------------------------------------------
// AlignableCaslAgent forward.  Inputs f32, outputs f32 (verified rounds 4-7).
// Round 7: tower-merged launches (blockIdx.y = tower), pack+zero kernels
// consolidated (27 -> 10 dispatches), convN BK=64 (half the barriers).
// ---------------------------------------------------------------------------

typedef unsigned short u16;
typedef unsigned int u32;
typedef __attribute__((ext_vector_type(8))) short bf16x8;
typedef __attribute__((ext_vector_type(4))) float f32x4;

__device__ __forceinline__ float b2f(u16 u) {
    union { u32 i; float f; } v; v.i = ((u32)u) << 16; return v.f;
}
__device__ __forceinline__ u16 f2b(float f) {
    union { float f; u32 i; } v; v.f = f;
    u32 r = v.i + 0x7fffu + ((v.i >> 16) & 1u);
    return (u16)(r >> 16);
}

// ---------------------------------------------------------------------------
// conv1 implicit-im2col MFMA, both towers (blockIdx.y).  x f32 [b][2][84][84],
// K=64 (k=ky*8+kx), N=32, S=4.  Out [t][m][32] bf16, m = b*400+oy*20+ox.
// Single staging round (K=64 = one BK).
// ---------------------------------------------------------------------------
__global__ __launch_bounds__(256) void conv1_mfma(
    const float* __restrict__ x, long boff,
    const u16* __restrict__ Wp,
    const float* __restrict__ bias_v, const float* __restrict__ bias_a,
    u16* __restrict__ outp, int Mtot)
{
    __shared__ __attribute__((aligned(16))) u16 As[128 * 72];

    const int tid = threadIdx.x;
    const int wave = tid >> 6, lane = tid & 63, quad = lane >> 4, l16 = lane & 15;
    const int m0 = blockIdx.x * 128;
    const int t = blockIdx.y;
    const u16* Wpt = Wp + t * 2048;
    const float* bias = t ? bias_a : bias_v;
    u16* outt = outp + (long)t * Mtot * 32;

    const int r = tid >> 1, h = tid & 1;
    int m = m0 + r; if (m > Mtot - 1) m = Mtot - 1;
    const int bl = m / 400, p = m % 400;
    const int oy = p / 20, ox = p % 20;
    const float* F = x + boff + (long)bl * 14112 + t * 7056
                     + (long)(oy * 4) * 84 + ox * 4;

    {
        u16 tmp[32];
#pragma unroll
        for (int rr = 0; rr < 4; ++rr) {
            const int ky = h * 4 + rr;
            float4 v0 = *(const float4*)(F + ky * 84);
            float4 v1 = *(const float4*)(F + ky * 84 + 4);
            tmp[rr * 8 + 0] = f2b(v0.x); tmp[rr * 8 + 1] = f2b(v0.y);
            tmp[rr * 8 + 2] = f2b(v0.z); tmp[rr * 8 + 3] = f2b(v0.w);
            tmp[rr * 8 + 4] = f2b(v1.x); tmp[rr * 8 + 5] = f2b(v1.y);
            tmp[rr * 8 + 6] = f2b(v1.z); tmp[rr * 8 + 7] = f2b(v1.w);
        }
        uint4* dst = (uint4*)(As + r * 72 + h * 32);
        const uint4* s = (const uint4*)tmp;
        dst[0] = s[0]; dst[1] = s[1]; dst[2] = s[2]; dst[3] = s[3];
    }
    __syncthreads();

    f32x4 acc[2][2];
#pragma unroll
    for (int mi = 0; mi < 2; ++mi)
#pragma unroll
        for (int ni = 0; ni < 2; ++ni)
            acc[mi][ni] = (f32x4){0.f, 0.f, 0.f, 0.f};

#pragma unroll
    for (int ks = 0; ks < 2; ++ks) {
        bf16x8 af[2], bf[2];
#pragma unroll
        for (int mi = 0; mi < 2; ++mi)
            af[mi] = *(const bf16x8*)(As + (wave * 32 + mi * 16 + l16) * 72
                                       + ks * 32 + quad * 8);
#pragma unroll
        for (int ni = 0; ni < 2; ++ni)
            bf[ni] = *(const bf16x8*)(Wpt + (ni * 16 + l16) * 64 + ks * 32 + quad * 8);
#pragma unroll
        for (int mi = 0; mi < 2; ++mi)
#pragma unroll
            for (int ni = 0; ni < 2; ++ni)
                acc[mi][ni] = __builtin_amdgcn_mfma_f32_16x16x32_bf16(
                    af[mi], bf[ni], acc[mi][ni], 0, 0, 0);
    }

#pragma unroll
    for (int mi = 0; mi < 2; ++mi)
#pragma unroll
        for (int ni = 0; ni < 2; ++ni) {
            const int col = ni * 16 + l16;
            const float bv = bias[col];
#pragma unroll
            for (int rr = 0; rr < 4; ++rr) {
                const int row = m0 + wave * 32 + mi * 16 + quad * 4 + rr;
                if (row < Mtot)
                    outt[(long)row * 32 + col] = f2b(fmaxf(acc[mi][ni][rr] + bv, 0.f));
            }
        }
}

// ---------------------------------------------------------------------------
// Generic NHWC bf16 conv, implicit-im2col MFMA, BK=64, both towers.
// in: [t][b][IH][IW][IC] bf16 (tower stride inTs), Wp: [t][OC][K] k-order
// (ky*KW+kx)*IC+ic.  64-k chunks are contiguous in NHWC (kx pairs share ky).
// ---------------------------------------------------------------------------
template<int IC, int IH, int IW, int OC, int KH, int KW, int S, int OH, int OW>
__global__ __launch_bounds__(256) void convN_mfma(
    const u16* __restrict__ in, long inTs,
    const u16* __restrict__ Wp, int WpTs,
    const float* __restrict__ bias_v, const float* __restrict__ bias_a,
    u16* __restrict__ outp, long outTs, int Mtot)
{
    constexpr int OP = OH * OW;
    constexpr int K  = KH * KW * IC;
    constexpr int NF = OC / 16;

    __shared__ __attribute__((aligned(16))) u16 As[128 * 72];

    const int tid = threadIdx.x;
    const int wave = tid >> 6, lane = tid & 63, quad = lane >> 4, l16 = lane & 15;
    const int m0 = blockIdx.x * 128;
    const int t = blockIdx.y;
    const u16* int_ = in + (long)t * inTs;
    const u16* Wpt = Wp + (long)t * WpTs;
    const float* bias = t ? bias_a : bias_v;
    u16* outt = outp + (long)t * outTs;

    const int r = tid >> 1, h = tid & 1;
    int m = m0 + r; if (m > Mtot - 1) m = Mtot - 1;
    const int bl = m / OP, p = m % OP;
    const int oy = p / OW, ox = p % OW;
    const u16* abase = int_ + (((long)bl * IH + oy * S) * IW + ox * S) * IC + h * 32;

    f32x4 acc[2][NF];
#pragma unroll
    for (int mi = 0; mi < 2; ++mi)
#pragma unroll
        for (int ni = 0; ni < NF; ++ni)
            acc[mi][ni] = (f32x4){0.f, 0.f, 0.f, 0.f};

    for (int k0 = 0; k0 < K; k0 += 64) {
        const int pos = k0 / IC;
        const int ky = pos / KW, kx = pos - ky * KW;
        const long aoff = ((long)ky * IW + kx) * IC;

        __syncthreads();
        {
            const uint4* src = (const uint4*)(abase + aoff);
            uint4 v0 = src[0], v1 = src[1], v2 = src[2], v3 = src[3];
            uint4* dst = (uint4*)(As + r * 72 + h * 32);
            dst[0] = v0; dst[1] = v1; dst[2] = v2; dst[3] = v3;
        }
        __syncthreads();

#pragma unroll
        for (int ks = 0; ks < 2; ++ks) {
            bf16x8 af[2], bf[NF];
#pragma unroll
            for (int mi = 0; mi < 2; ++mi)
                af[mi] = *(const bf16x8*)(As + (wave * 32 + mi * 16 + l16) * 72
                                           + ks * 32 + quad * 8);
#pragma unroll
            for (int ni = 0; ni < NF; ++ni)
                bf[ni] = *(const bf16x8*)(Wpt + (long)(ni * 16 + l16) * K
                                           + k0 + ks * 32 + quad * 8);
#pragma unroll
            for (int mi = 0; mi < 2; ++mi)
#pragma unroll
                for (int ni = 0; ni < NF; ++ni)
                    acc[mi][ni] = __builtin_amdgcn_mfma_f32_16x16x32_bf16(
                        af[mi], bf[ni], acc[mi][ni], 0, 0, 0);
        }
    }

#pragma unroll
    for (int mi = 0; mi < 2; ++mi)
#pragma unroll
        for (int ni = 0; ni < NF; ++ni) {
            const int col = ni * 16 + l16;
            const float bv = bias[col];
#pragma unroll
            for (int rr = 0; rr < 4; ++rr) {
                const int row = m0 + wave * 32 + mi * 16 + quad * 4 + rr;
                if (row < Mtot)
                    outt[(long)row * OC + col] = f2b(fmaxf(acc[mi][ni][rr] + bv, 0.f));
            }
        }
}

// ---------------------------------------------------------------------------
// Split-K MFMA GEMM with per-M-tile B select (tower merge):
// C[M][N] f32 += A[M][K] * (B[N][K])^T, B = (m0 < Mhalf) ? B0 : B1.
// C pre-zeroed; atomicAdd epilogue.  128x128 tile, BK=32.
// ---------------------------------------------------------------------------
#define LDSP 40
__global__ __launch_bounds__(256) void gemm_sk2(
    const u16* __restrict__ A, const u16* __restrict__ B0,
    const u16* __restrict__ B1,
    float* __restrict__ C, int M, int Mhalf, int N, int K, int Kc)
{
    __shared__ __attribute__((aligned(16))) u16 As[128 * LDSP];
    __shared__ __attribute__((aligned(16))) u16 Bs[128 * LDSP];

    const int tid  = threadIdx.x;
    const int wave = tid >> 6, lane = tid & 63;
    const int quad = lane >> 4, l16 = lane & 15;
    const int m0 = blockIdx.y * 128, n0 = blockIdx.x * 128;
    const u16* B = (m0 < Mhalf) ? B0 : B1;
    const int wm = (wave >> 1) * 64, wn = (wave & 1) * 64;
    const int kfrom = blockIdx.z * Kc;
    int kto = kfrom + Kc; if (kto > K) kto = K;

    f32x4 acc[4][4];
#pragma unroll
    for (int mi = 0; mi < 4; ++mi)
#pragma unroll
        for (int ni = 0; ni < 4; ++ni)
            acc[mi][ni] = (f32x4){0.f, 0.f, 0.f, 0.f};

    for (int k0 = kfrom; k0 < kto; k0 += 32) {
        __syncthreads();
#pragma unroll
        for (int pass = 0; pass < 2; ++pass) {
            int idx = tid + pass * 256;
            int r = idx >> 2, seg = idx & 3;
            int gr = m0 + r; if (gr > M - 1) gr = M - 1;
            uint4 va = *(const uint4*)(A + (long)gr * K + k0 + seg * 8);
            *(uint4*)(As + r * LDSP + seg * 8) = va;
            uint4 vb = *(const uint4*)(B + (long)(n0 + r) * K + k0 + seg * 8);
            *(uint4*)(Bs + r * LDSP + seg * 8) = vb;
        }
        __syncthreads();

        bf16x8 af[4], bfr[4];
#pragma unroll
        for (int mi = 0; mi < 4; ++mi)
            af[mi] = *(const bf16x8*)(As + (wm + mi * 16 + l16) * LDSP + quad * 8);
#pragma unroll
        for (int ni = 0; ni < 4; ++ni)
            bfr[ni] = *(const bf16x8*)(Bs + (wn + ni * 16 + l16) * LDSP + quad * 8);
#pragma unroll
        for (int mi = 0; mi < 4; ++mi)
#pragma unroll
            for (int ni = 0; ni < 4; ++ni)
                acc[mi][ni] = __builtin_amdgcn_mfma_f32_16x16x32_bf16(
                    af[mi], bfr[ni], acc[mi][ni], 0, 0, 0);
    }

#pragma unroll
    for (int mi = 0; mi < 4; ++mi)
#pragma unroll
        for (int ni = 0; ni < 4; ++ni) {
            int col = n0 + wn + ni * 16 + l16;
#pragma unroll
            for (int rr = 0; rr < 4; ++rr) {
                int row = m0 + wm + mi * 16 + quad * 4 + rr;
                if (row < M) atomicAdd(&C[(long)row * N + col], acc[mi][ni][rr]);
            }
        }
}

// ---------------------------------------------------------------------------
// Wl [512][3136] (k = oc*49+p) -> [n][p*64+oc] bf16 via LDS row transpose.
// Blocks 0..511: vWl -> Wlb[0], 512..1023: aWl -> Wlb[1].
// ---------------------------------------------------------------------------
__global__ __launch_bounds__(256) void pack_wl(
    const float* __restrict__ vWl, const float* __restrict__ aWl,
    u16* __restrict__ dst)
{
    __shared__ float row[3136];
    const int bid = blockIdx.x, tid = threadIdx.x;
    const int n = bid & 511;
    const float* src = (bid < 512) ? vWl : aWl;
    for (int i = tid; i < 3136; i += 256)
        row[i] = src[(long)n * 3136 + i];
    __syncthreads();
    u16* d = dst + (long)bid * 3136;
    for (int i = tid; i < 3136; i += 256) {
        int p = i >> 6, oc = i & 63;
        d[i] = f2b(row[oc * 49 + p]);
    }
}

// ---------------------------------------------------------------------------
// All small weight packs + output-accumulator zeroing in ONE kernel.
// Flat index sections; zbase covers gates(524288 f32) + ych(1048576 f32),
// carved contiguously.  Grid = 2,080,768/256 = 8128 blocks exactly.
// ---------------------------------------------------------------------------
__global__ __launch_bounds__(256) void pack_misc(
    const float* __restrict__ vW1, const float* __restrict__ aW1,
    const float* __restrict__ vW2, const float* __restrict__ aW2,
    const float* __restrict__ vW3, const float* __restrict__ aW3,
    const float* __restrict__ avW, const float* __restrict__ aaW,
    const float* __restrict__ asW,
    const float* __restrict__ Wih, const float* __restrict__ Whh,
    u16* __restrict__ Wp1, u16* __restrict__ Wp2, u16* __restrict__ Wp3,
    u16* __restrict__ WTatt, u16* __restrict__ Bcat,
    float* __restrict__ zbase)
{
    const int idx = blockIdx.x * 256 + threadIdx.x;
    if (idx < 4096) {                            // Wp1: [t][32][64], src flat OIHW
        const float* s = (idx < 2048) ? vW1 : aW1;
        Wp1[idx] = f2b(s[idx & 2047]);
    } else if (idx < 69632) {                    // Wp2: [t][64][(ky*4+kx)*32+ic]
        int i = idx - 4096;
        const float* s = (i < 32768) ? vW2 : aW2;
        int j = i & 32767;
        int oc = j >> 9, kk = j & 511;
        int pos = kk >> 5, ic = kk & 31;
        int ky = pos >> 2, kx = pos & 3;
        Wp2[i] = f2b(s[((oc * 32 + ic) * 4 + ky) * 4 + kx]);
    } else if (idx < 143360) {                   // Wp3: [t][64][(ky*3+kx)*64+ic]
        int i = idx - 69632;
        const float* s = (i < 36864) ? vW3 : aW3;
        int j = i % 36864;
        int oc = j / 576, kk = j % 576;
        int pos = kk >> 6, ic = kk & 63;
        int ky = pos / 3, kx = pos % 3;
        Wp3[i] = f2b(s[((oc * 64 + ic) * 3 + ky) * 3 + kx]);
    } else if (idx < 180224) {                   // WTatt: [1152][32]
        int i = idx - 143360;
        int k = i >> 5, j = i & 31;
        float v = (k < 512) ? avW[(long)j * 512 + k]
                : (k < 1024) ? aaW[(long)j * 512 + (k - 512)]
                : asW[(long)j * 128 + (k - 1024)];
        WTatt[i] = f2b(v);
    } else if (idx < 507904) {                   // Bcat: [512][640]
        int i = idx - 180224;
        int n = i / 640, k = i % 640;
        Bcat[i] = f2b((k < 512) ? Wih[(long)n * 512 + k]
                                : Whh[(long)n * 128 + (k - 512)]);
    } else {                                     // zero gates+ych (1,572,864 f32)
        zbase[idx - 507904] = 0.f;
    }
}

// ---------------------------------------------------------------------------
// bias + ReLU + LayerNorm, both towers (b 0..2047; tower = b>>10).
// Writes f32 to out slot (vf then af, contiguous).
// ---------------------------------------------------------------------------
__global__ __launch_bounds__(256) void ln_relu(
    const float* __restrict__ y,
    const float* __restrict__ bl_v, const float* __restrict__ bl_a,
    const float* __restrict__ g_v,  const float* __restrict__ g_a,
    const float* __restrict__ be_v, const float* __restrict__ be_a,
    float* __restrict__ outv)
{
    __shared__ float red[256];
    __shared__ float mean_s, inv_s;

    const int b = blockIdx.x, tid = threadIdx.x;
    const int t = b >> 10;
    const float* bias = t ? bl_a : bl_v;
    const float* g    = t ? g_a  : g_v;
    const float* be   = t ? be_a : be_v;
    const float* yr = y + (long)b * 512;

    float v0 = fmaxf(yr[tid]       + bias[tid],       0.f);
    float v1 = fmaxf(yr[tid + 256] + bias[tid + 256], 0.f);

    red[tid] = v0 + v1;
    __syncthreads();
    for (int s = 128; s > 0; s >>= 1) { if (tid < s) red[tid] += red[tid + s]; __syncthreads(); }
    if (tid == 0) mean_s = red[0] * (1.f / 512.f);
    __syncthreads();
    float mean = mean_s;
    float d0 = v0 - mean, d1 = v1 - mean;
    red[tid] = d0 * d0 + d1 * d1;
    __syncthreads();
    for (int s = 128; s > 0; s >>= 1) { if (tid < s) red[tid] += red[tid + s]; __syncthreads(); }
    if (tid == 0) inv_s = rsqrtf(red[0] * (1.f / 512.f) + 1e-5f);
    __syncthreads();
    float inv = inv_s;

    outv[(long)b * 512 + tid]       = d0 * inv * g[tid]       + be[tid];
    outv[(long)b * 512 + tid + 256] = d1 * inv * g[tid + 256] + be[tid + 256];
}

// ---------------------------------------------------------------------------
// Attention gating -> Acat row = [fused (512) | (1-done)*h0 (128)] bf16.
// Coalesced transposed weights WT[1152][32].
// ---------------------------------------------------------------------------
__global__ __launch_bounds__(256) void attn_fuse(
    const float* __restrict__ vff, const float* __restrict__ aff,
    const float* __restrict__ h0, const float* __restrict__ done,
    const u16* __restrict__ WT,
    const float* __restrict__ avb, const float* __restrict__ aab,
    const float* __restrict__ asb,
    const float* __restrict__ attW, const float* __restrict__ attb,
    u16* __restrict__ Acat)
{
    __shared__ float vs[512], afs[512], hs[128], part[8][32], act[32], wsm[2];
    const int b = blockIdx.x, tid = threadIdx.x;

    for (int i = tid; i < 512; i += 256) {
        vs[i]  = vff[(long)b * 512 + i];
        afs[i] = aff[(long)b * 512 + i];
    }
    if (tid < 128) hs[tid] = h0[b * 128 + tid];
    __syncthreads();

    {
        const int j = tid & 31, g = tid >> 5;
        float a = 0.f;
#pragma unroll 8
        for (int k = g * 64; k < g * 64 + 64; ++k)
            a += vs[k] * b2f(WT[k * 32 + j]);
#pragma unroll 8
        for (int k = g * 64; k < g * 64 + 64; ++k)
            a += afs[k] * b2f(WT[(512 + k) * 32 + j]);
#pragma unroll 8
        for (int k = g * 16; k < g * 16 + 16; ++k)
            a += hs[k] * b2f(WT[(1024 + k) * 32 + j]);
        part[g][j] = a;
    }
    __syncthreads();
    if (tid < 32) {
        float a = avb[tid] + aab[tid] + asb[tid];
#pragma unroll
        for (int g2 = 0; g2 < 8; ++g2) a += part[g2][tid];
        act[tid] = tanhf(a);
    }
    __syncthreads();
    if (tid == 0) {
        float l0 = attb[0], l1 = attb[1];
        for (int j = 0; j < 32; ++j) {
            l0 += act[j] * attW[j];
            l1 += act[j] * attW[32 + j];
        }
        float mx = fmaxf(l0, l1);
        float e0 = expf(l0 - mx), e1 = expf(l1 - mx);
        float s = e0 + e1;
        wsm[0] = e0 / s; wsm[1] = e1 / s;
    }
    __syncthreads();
    const float w0 = wsm[0], w1 = wsm[1];
    const float m = 1.f - done[b];
    for (int i = tid; i < 512; i += 256)
        Acat[(long)b * 640 + i] = f2b(w0 * vs[i] + w1 * afs[i]);
    if (tid < 128)
        Acat[(long)b * 640 + 512 + tid] = f2b(m * hs[tid]);
}

// ---------------------------------------------------------------------------
// LSTM pointwise epilogue (gate order i,f,g,o).  Writes f32 h_new, c_new.
// ---------------------------------------------------------------------------
__global__ __launch_bounds__(128) void lstm_fin(
    const float* __restrict__ gates,
    const float* __restrict__ bih, const float* __restrict__ bhh,
    const float* __restrict__ c0, const float* __restrict__ done,
    float* __restrict__ out)
{
    const int b = blockIdx.x, j = threadIdx.x;
    const float* G = gates + (long)b * 512;
    float gi = G[j]       + bih[j]       + bhh[j];
    float gf = G[128 + j] + bih[128 + j] + bhh[128 + j];
    float gg = G[256 + j] + bih[256 + j] + bhh[256 + j];
    float go = G[384 + j] + bih[384 + j] + bhh[384 + j];
    float m  = 1.f - done[b];
    float c  = m * c0[b * 128 + j];
    float si = 1.f / (1.f + expf(-gi));
    float sf = 1.f / (1.f + expf(-gf));
    float so = 1.f / (1.f + expf(-go));
    float cn = sf * c + si * tanhf(gg);
    float hn = so * tanhf(cn);
    out[b * 128 + j]          = hn;
    out[131072 + b * 128 + j] = cn;
}

// ---------------------------------------------------------------------------
extern "C" void kernel_launch(void* const* d_in, const int* in_sizes, int n_in,
                              void* d_out, int out_size, void* d_ws, size_t ws_size,
                              hipStream_t stream)
{
    (void)in_sizes; (void)n_in; (void)out_size;

    const float* x     = (const float*)d_in[0];
    const float* done  = (const float*)d_in[1];
    const float* h0    = (const float*)d_in[2];
    const float* c0in  = (const float*)d_in[3];
    const float* vW1   = (const float*)d_in[4];
    const float* vb1   = (const float*)d_in[5];
    const float* vW2   = (const float*)d_in[6];
    const float* vb2   = (const float*)d_in[7];
    const float* vW3   = (const float*)d_in[8];
    const float* vb3   = (const float*)d_in[9];
    const float* vWl   = (const float*)d_in[10];
    const float* vbl   = (const float*)d_in[11];
    const float* aW1   = (const float*)d_in[12];
    const float* ab1   = (const float*)d_in[13];
    const float* aW2   = (const float*)d_in[14];
    const float* ab2   = (const float*)d_in[15];
    const float* aW3   = (const float*)d_in[16];
    const float* ab3   = (const float*)d_in[17];
    const float* aWl   = (const float*)d_in[18];
    const float* abl   = (const float*)d_in[19];
    const float* vln_g = (const float*)d_in[20];
    const float* vln_b = (const float*)d_in[21];
    const float* aln_g = (const float*)d_in[22];
    const float* aln_b = (const float*)d_in[23];
    const float* att_vW = (const float*)d_in[24];
    const float* att_vb = (const float*)d_in[25];
    const float* att_aW = (const float*)d_in[26];
    const float* att_ab = (const float*)d_in[27];
    const float* att_sW = (const float*)d_in[28];
    const float* att_sb = (const float*)d_in[29];
    const float* attW  = (const float*)d_in[30];
    const float* attb  = (const float*)d_in[31];
    const float* Wih   = (const float*)d_in[32];
    const float* Whh   = (const float*)d_in[33];
    const float* bih   = (const float*)d_in[34];
    const float* bhh   = (const float*)d_in[35];

    float* out = (float*)d_out;
    float* vfaf = out + 262144;   // [2048][512] f32 (vf then af)

    // ---- adaptive batch chunk (towers processed together) ----
    const size_t PERBATCH = 2ul * (12800 + 5184) * 2;   // c1 + c2, both towers
    const size_t PERSIST  =
          1024ul * 512 * 4       // gates
        + 2048ul * 512 * 4       // ych (both towers)
        + 1024ul * 640 * 2       // Acat
        + 512ul * 640 * 2        // Bcat
        + 2ul * 512 * 3136 * 2   // Wlb
        + 2ul * 2048 * 2         // Wp1
        + 2ul * 32768 * 2        // Wp2
        + 2ul * 36864 * 2        // Wp3
        + 36864ul * 2            // WTatt
        + 2ul * 1024 * 3136 * 2; // c3f (both towers)
    int NB = 64;
    const int cands[4] = {1024, 512, 256, 128};
    for (int i = 0; i < 4; ++i)
        if (PERSIST + (size_t)cands[i] * PERBATCH <= ws_size) { NB = cands[i]; break; }
    const int NC = 1024 / NB;

    // ---- workspace carve (gates then ych MUST be contiguous for pack_misc) --
    char* p = (char*)d_ws;
    float* gates = (float*)p; p += 1024ul * 512 * 4;
    float* ych   = (float*)p; p += 2048ul * 512 * 4;
    u16*   Acat  = (u16*)p;   p += 1024ul * 640 * 2;
    u16*   Bcat  = (u16*)p;   p += 512ul * 640 * 2;
    u16*   Wlb   = (u16*)p;   p += 2ul * 512 * 3136 * 2;
    u16*   Wp1   = (u16*)p;   p += 2ul * 2048 * 2;
    u16*   Wp2   = (u16*)p;   p += 2ul * 32768 * 2;
    u16*   Wp3   = (u16*)p;   p += 2ul * 36864 * 2;
    u16*   WTatt = (u16*)p;   p += 36864ul * 2;
    u16*   c3f   = (u16*)p;   p += 2ul * 1024 * 3136 * 2;
    u16*   c1    = (u16*)p;   p += 2ul * NB * 12800 * 2;
    u16*   c2    = (u16*)p;

    // 1) packs + zeros
    hipLaunchKernelGGL(pack_wl, dim3(1024), dim3(256), 0, stream, vWl, aWl, Wlb);
    hipLaunchKernelGGL(pack_misc, dim3(8128), dim3(256), 0, stream,
        vW1, aW1, vW2, aW2, vW3, aW3, att_vW, att_aW, att_sW, Wih, Whh,
        Wp1, Wp2, Wp3, WTatt, Bcat, gates);

    // 2) conv towers (both towers per launch via blockIdx.y)
    for (int cch = 0; cch < NC; ++cch) {
        const int b0 = cch * NB;
        const int M1 = NB * 400, M2 = NB * 81, M3 = NB * 49;

        hipLaunchKernelGGL(conv1_mfma, dim3(M1 / 128, 2), dim3(256), 0, stream,
            x, (long)b0 * 14112, Wp1, vb1, ab1, c1, M1);

        hipLaunchKernelGGL((convN_mfma<32, 20, 20, 64, 4, 4, 2, 9, 9>),
            dim3((M2 + 127) / 128, 2), dim3(256), 0, stream,
            c1, (long)NB * 12800, Wp2, 32768, vb2, ab2,
            c2, (long)NB * 5184, M2);

        hipLaunchKernelGGL((convN_mfma<64, 9, 9, 64, 3, 3, 1, 7, 7>),
            dim3((M3 + 127) / 128, 2), dim3(256), 0, stream,
            c2, (long)NB * 5184, Wp3, 36864, vb3, ab3,
            c3f + (long)b0 * 3136, 1024l * 3136, M3);
    }

    // 3) tower linears as one M=2048 GEMM (B switches at row 1024), split-K 7
    hipLaunchKernelGGL(gemm_sk2, dim3(4, 16, 7), dim3(256), 0, stream,
        c3f, Wlb, Wlb + 512ul * 3136, ych, 2048, 1024, 512, 3136, 448);

    // 4) LN both towers -> vf/af f32 slots in d_out
    hipLaunchKernelGGL(ln_relu, dim3(2048), dim3(256), 0, stream,
        ych, vbl, abl, vln_g, aln_g, vln_b, aln_b, vfaf);

    // 5) attention gating -> Acat
    hipLaunchKernelGGL(attn_fuse, dim3(1024), dim3(256), 0, stream,
        vfaf, vfaf + 1024ul * 512, h0, done, WTatt,
        att_vb, att_ab, att_sb, attW, attb, Acat);

    // 6) gates GEMM (split-K 4)
    hipLaunchKernelGGL(gemm_sk2, dim3(4, 8, 4), dim3(256), 0, stream,
        Acat, Bcat, Bcat, gates, 1024, 1 << 30, 512, 640, 160);

    // 7) LSTM epilogue
    hipLaunchKernelGGL(lstm_fin, dim3(1024), dim3(128), 0, stream,
        gates, bih, bhh, c0in, done, out);
}